// Round 8
// baseline (210.566 us; speedup 1.0000x reference)
//
#include <hip/hip_runtime.h>

typedef __bf16 bf16x8 __attribute__((ext_vector_type(8)));
typedef float  f32x4  __attribute__((ext_vector_type(4)));

#define TSEQ 2048
#define CDIM 1024
#define NHEAD 16
#define DH 64
#define SCALE2 0.1803368801111137f  // 0.125 * log2(e)

__device__ __forceinline__ void gl_lds16(const void* g, void* l) {
  __builtin_amdgcn_global_load_lds(
      (const __attribute__((address_space(1))) unsigned int*)g,
      (__attribute__((address_space(3))) unsigned int*)l, 16, 0, 0);
}

__device__ __forceinline__ float fexp2(float x) { return __builtin_amdgcn_exp2f(x); }

// DPP cross-lane (VALU pipe). Reduce over each 16-lane row.
template <int CTRL>
__device__ __forceinline__ float dppmov(float x) {
  return __int_as_float(__builtin_amdgcn_update_dpp(
      0, __float_as_int(x), CTRL, 0xF, 0xF, true));
}
__device__ __forceinline__ float redmax16(float x) {
  x = fmaxf(x, dppmov<0xB1>(x));
  x = fmaxf(x, dppmov<0x4E>(x));
  x = fmaxf(x, dppmov<0x124>(x));
  x = fmaxf(x, dppmov<0x128>(x));
  return x;
}
__device__ __forceinline__ float redsum16(float x) {
  x += dppmov<0xB1>(x);
  x += dppmov<0x4E>(x);
  x += dppmov<0x124>(x);
  x += dppmov<0x128>(x);
  return x;
}

// ---------------- fp32 -> bf16 conversion (vectorized) ----------------
__global__ __launch_bounds__(256) void cvt_bf16(const float* __restrict__ in,
                                                __bf16* __restrict__ out, int n8) {
  int i = blockIdx.x * 256 + threadIdx.x;
  if (i >= n8) return;
  const float4* p = (const float4*)(in + (size_t)i * 8);
  float4 a = p[0], b = p[1];
  bf16x8 r;
  r[0] = (__bf16)a.x; r[1] = (__bf16)a.y; r[2] = (__bf16)a.z; r[3] = (__bf16)a.w;
  r[4] = (__bf16)b.x; r[5] = (__bf16)b.y; r[6] = (__bf16)b.z; r[7] = (__bf16)b.w;
  *(bf16x8*)(out + (size_t)i * 8) = r;
}

// ---------------- bf16 GEMM (m97-style): out[M,N] = A[M,K]*Bw[N,K]^T + bias --------
// EPI=1 scatters qkv; q is PRE-SCALED by 0.125*log2e.
template <int EPI>
__global__ __launch_bounds__(256) void gemm_bt(
    const __bf16* __restrict__ A, const __bf16* __restrict__ Bw,
    const float* __restrict__ bias, float* __restrict__ outf,
    __bf16* __restrict__ q_buf, __bf16* __restrict__ k_buf,
    __bf16* __restrict__ vT_buf, int M, int N, int K) {
  __shared__ alignas(16) __bf16 lda[128 * 64];
  __shared__ alignas(16) __bf16 ldb[128 * 64];
  const int tid = threadIdx.x;
  const int lane = tid & 63, wid = tid >> 6;
  const int wm = wid >> 1, wn = wid & 1;
  const int row0 = blockIdx.y * 128, col0 = blockIdx.x * 128;
  f32x4 acc[4][4] = {};

  const int srow = lane >> 3;
  const int scb = (lane & 7) * 16;

  for (int k0 = 0; k0 < K; k0 += 64) {
#pragma unroll
    for (int j = 0; j < 4; ++j) {
      int blk = j * 4 + wid;
      int r = blk * 8 + srow;
      char* la = (char*)lda + blk * 1024;
      char* lb = (char*)ldb + blk * 1024;
      gl_lds16((const char*)(A + (size_t)(row0 + r) * K + k0) + scb, la);
      gl_lds16((const char*)(Bw + (size_t)(col0 + r) * K + k0) + scb, lb);
    }
    __syncthreads();
#pragma unroll
    for (int kk = 0; kk < 2; ++kk) {
      bf16x8 af[4], bfr[4];
#pragma unroll
      for (int m = 0; m < 4; ++m)
        af[m] = *(const bf16x8*)&lda[(wm * 64 + m * 16 + (lane & 15)) * 64 + kk * 32 + (lane >> 4) * 8];
#pragma unroll
      for (int n = 0; n < 4; ++n)
        bfr[n] = *(const bf16x8*)&ldb[(wn * 64 + n * 16 + (lane & 15)) * 64 + kk * 32 + (lane >> 4) * 8];
#pragma unroll
      for (int m = 0; m < 4; ++m)
#pragma unroll
        for (int n = 0; n < 4; ++n)
          acc[m][n] = __builtin_amdgcn_mfma_f32_16x16x32_bf16(af[m], bfr[n], acc[m][n], 0, 0, 0);
    }
    __syncthreads();
  }
#pragma unroll
  for (int m = 0; m < 4; ++m) {
#pragma unroll
    for (int n = 0; n < 4; ++n) {
#pragma unroll
      for (int i = 0; i < 4; ++i) {
        int r = row0 + wm * 64 + m * 16 + (lane >> 4) * 4 + i;
        int c = col0 + wn * 64 + n * 16 + (lane & 15);
        float v = acc[m][n][i] + bias[c];
        if (EPI == 0) {
          outf[(size_t)r * N + c] = v;
        } else {
          int bb = r >> 11, t = r & 2047;
          int sec = c >> 10, cc = c & 1023;
          int hh = cc >> 6, d = cc & 63;
          size_t bh = (size_t)bb * NHEAD + hh;
          if (sec == 0)      q_buf[(bh * TSEQ + (size_t)t) * DH + d] = (__bf16)(v * SCALE2);
          else if (sec == 1) k_buf[(bh * TSEQ + (size_t)t) * DH + d] = (__bf16)v;
          else               vT_buf[(bh * DH + (size_t)d) * TSEQ + t] = (__bf16)v;
        }
      }
    }
  }
}

// ---------------- flash attention: split-K pairs, 4 wave-tasks per 256-thr block ----
// Wave wid handles pair {127-wv, wv}, wv=(blockIdx.y>>1)*4+wid, half hf=blockIdx.y&1.
// All 4 waves same bh, within <=1 tile of work -> uniform block lifetime, no barriers.
// 1024 blocks = 4 blocks/CU x 4 waves = 16 waves/CU @128 VGPR (beats the ~8/CU
// single-wave workgroup residency cap seen in R4/R5/R7).
template <bool MASK>
__device__ __forceinline__ void qk_softmax_p(
    int kt, int qrow0, int lane, float ktb, const float* pre_n,
    const bf16x8* qf, const bf16x8 (*kf)[2],
    f32x4* o, float* mrow, float* lrow, __bf16 (*p)[68]) {
  f32x4 s[4];
#pragma unroll
  for (int n = 0; n < 4; ++n) {
    f32x4 z = {};
    z = __builtin_amdgcn_mfma_f32_16x16x32_bf16(qf[0], kf[n][0], z, 0, 0, 0);
    s[n] = __builtin_amdgcn_mfma_f32_16x16x32_bf16(qf[1], kf[n][1], z, 0, 0, 0);
  }
  const int qr0 = qrow0 + (lane >> 4) * 4;
  float sv[4][4];
  float tmax[4] = {-__builtin_inff(), -__builtin_inff(), -__builtin_inff(), -__builtin_inff()};
#pragma unroll
  for (int n = 0; n < 4; ++n) {
    const float cb = ktb + pre_n[n];  // slope2 * kc
    const int kc = kt + n * 16 + (lane & 15);
#pragma unroll
    for (int i = 0; i < 4; ++i) {
      float x = s[n][i] + cb;
      if (MASK) x = (kc <= qr0 + i) ? x : -__builtin_inff();
      sv[n][i] = x;
      tmax[i] = fmaxf(tmax[i], x);
    }
  }
#pragma unroll
  for (int i = 0; i < 4; ++i) {
    float t = redmax16(tmax[i]);
    float mnew = fmaxf(mrow[i], t);
    float corr = fexp2(mrow[i] - mnew);
    mrow[i] = mnew;
    float pf[4];
#pragma unroll
    for (int n = 0; n < 4; ++n) pf[n] = fexp2(sv[n][i] - mnew);
    float rs = redsum16((pf[0] + pf[1]) + (pf[2] + pf[3]));
    lrow[i] = lrow[i] * corr + rs;
#pragma unroll
    for (int n2 = 0; n2 < 4; ++n2) o[n2][i] *= corr;
#pragma unroll
    for (int n = 0; n < 4; ++n)
      p[(lane >> 4) * 4 + i][n * 16 + (lane & 15)] = (__bf16)pf[n];
  }
}

__device__ __forceinline__ void pv_acc(
    int lane, const bf16x8 (*vf)[2], f32x4* o, const __bf16 (*p)[68]) {
  bf16x8 pa[2];
#pragma unroll
  for (int kk = 0; kk < 2; ++kk)
    pa[kk] = *(const bf16x8*)&p[lane & 15][kk * 32 + (lane >> 4) * 8];
#pragma unroll
  for (int n2 = 0; n2 < 4; ++n2) {
    o[n2] = __builtin_amdgcn_mfma_f32_16x16x32_bf16(pa[0], vf[n2][0], o[n2], 0, 0, 0);
    o[n2] = __builtin_amdgcn_mfma_f32_16x16x32_bf16(pa[1], vf[n2][1], o[n2], 0, 0, 0);
  }
}

__global__ __launch_bounds__(256) void attn_fwd(
    const __bf16* __restrict__ q_buf, const __bf16* __restrict__ k_buf,
    const __bf16* __restrict__ vT_buf, __bf16* __restrict__ o_part,
    float* __restrict__ ml_part) {
  const int T = TSEQ;
  const int tid = threadIdx.x;
  const int lane = tid & 63, wid = tid >> 6;
  const int bh = blockIdx.x;
  const int wv = (blockIdx.y >> 1) * 4 + wid;
  const int hf = blockIdx.y & 1;
  const int h = bh & 15;
  const int grp[2] = {127 - wv, wv};  // heavy, light
  const int row0[2] = {grp[0] * 16, grp[1] * 16};
  const int nT[2] = {grp[0] / 4 + 1, grp[1] / 4 + 1};
  const int lastT[2] = {grp[0] / 4, grp[1] / 4};
  const float slope2 = exp2f(-0.5f * (float)(h + 1)) * 1.44269504f;
  const __bf16* qp = q_buf + (size_t)bh * T * DH;
  const __bf16* kp = k_buf + (size_t)bh * T * DH;
  const __bf16* vp = vT_buf + (size_t)bh * DH * T;

  __shared__ alignas(16) __bf16 p_lds[4][2][16][68];

  bf16x8 qf[2][2];
#pragma unroll
  for (int g = 0; g < 2; ++g) {
    const __bf16* qr = &qp[(size_t)(row0[g] + (lane & 15)) * DH + (lane >> 4) * 8];
    qf[g][0] = *(const bf16x8*)qr;
    qf[g][1] = *(const bf16x8*)(qr + 32);
  }

  f32x4 o[2][4] = {};
  float mrow[2][4], lrow[2][4];
#pragma unroll
  for (int g = 0; g < 2; ++g)
#pragma unroll
    for (int i = 0; i < 4; ++i) { mrow[g][i] = -__builtin_inff(); lrow[g][i] = 0.f; }

  const int klo = (lane & 15) * DH + (lane >> 4) * 8;
  const int vlo = (lane & 15) * T + (lane >> 4) * 8;

  float pre_n[4];
#pragma unroll
  for (int n = 0; n < 4; ++n) pre_n[n] = slope2 * (float)(n * 16 + (lane & 15));

  bf16x8 kf[4][2];
  {
    const int kt0 = hf * 64;
#pragma unroll
    for (int n = 0; n < 4; ++n) {
      const __bf16* kr = kp + (size_t)(kt0 + n * 16) * DH + klo;
      kf[n][0] = *(const bf16x8*)kr;
      kf[n][1] = *(const bf16x8*)(kr + 32);
    }
  }

  for (int j = hf; j < nT[0]; j += 2) {
    const int kt = j * 64;
    bf16x8 vf[4][2];
#pragma unroll
    for (int n2 = 0; n2 < 4; ++n2) {
      const __bf16* vr = vp + vlo + n2 * 16 * T + kt;
      vf[n2][0] = *(const bf16x8*)vr;
      vf[n2][1] = *(const bf16x8*)(vr + 32);
    }
    bf16x8 kn[4][2];
    const bool pre = (j + 2 < nT[0]);
    if (pre) {
#pragma unroll
      for (int n = 0; n < 4; ++n) {
        const __bf16* kr = kp + (size_t)(kt + 128 + n * 16) * DH + klo;
        kn[n][0] = *(const bf16x8*)kr;
        kn[n][1] = *(const bf16x8*)(kr + 32);
      }
    }
    const float ktb = slope2 * (float)kt;
    const bool l_act = (j < nT[1]);
    if (j == lastT[0])
      qk_softmax_p<true>(kt, row0[0], lane, ktb, pre_n, qf[0], kf, o[0], mrow[0], lrow[0], p_lds[wid][0]);
    else
      qk_softmax_p<false>(kt, row0[0], lane, ktb, pre_n, qf[0], kf, o[0], mrow[0], lrow[0], p_lds[wid][0]);
    if (l_act) {
      if (j == lastT[1])
        qk_softmax_p<true>(kt, row0[1], lane, ktb, pre_n, qf[1], kf, o[1], mrow[1], lrow[1], p_lds[wid][1]);
      else
        qk_softmax_p<false>(kt, row0[1], lane, ktb, pre_n, qf[1], kf, o[1], mrow[1], lrow[1], p_lds[wid][1]);
    }
    pv_acc(lane, vf, o[0], p_lds[wid][0]);
    if (l_act) pv_acc(lane, vf, o[1], p_lds[wid][1]);
    if (pre) {
#pragma unroll
      for (int n = 0; n < 4; ++n) {
        kf[n][0] = kn[n][0];
        kf[n][1] = kn[n][1];
      }
    }
  }

  // write partials
  const size_t pbase = (size_t)hf * 4096 + (size_t)bh * 128;
#pragma unroll
  for (int g = 0; g < 2; ++g) {
    const size_t gb = (pbase + grp[g]) * 1024;
#pragma unroll
    for (int i = 0; i < 4; ++i)
#pragma unroll
      for (int n2 = 0; n2 < 4; ++n2)
        o_part[gb + (size_t)(((lane >> 4) * 4 + i) * 64 + n2 * 16 + (lane & 15))] =
            (__bf16)o[g][n2][i];
    if ((lane & 15) == 0) {
      float* mlp = ml_part + (pbase + grp[g]) * 32;
#pragma unroll
      for (int i = 0; i < 4; ++i) {
        mlp[(lane >> 4) * 4 + i] = mrow[g][i];
        mlp[16 + (lane >> 4) * 4 + i] = lrow[g][i];
      }
    }
  }
}

// ---------------- combine the two K-halves ----------------
__global__ __launch_bounds__(256) void attn_combine(
    const __bf16* __restrict__ o_part, const float* __restrict__ ml_part,
    __bf16* __restrict__ y_buf) {
  const int lane = threadIdx.x & 63;          // d
  const int grp = blockIdx.x * 4 + (threadIdx.x >> 6);  // bh*128 + g
  const int bh = grp >> 7, g = grp & 127;
  const int b = bh >> 4, h = bh & 15;
  const float* ml0 = ml_part + (size_t)grp * 32;
  const float* ml1 = ml_part + (size_t)(4096 + grp) * 32;
  const __bf16* op0 = o_part + (size_t)grp * 1024;
  const __bf16* op1 = o_part + (size_t)(4096 + grp) * 1024;
#pragma unroll 4
  for (int r = 0; r < 16; ++r) {
    float m0 = ml0[r], l0 = ml0[16 + r];
    float m1 = ml1[r], l1 = ml1[16 + r];
    float mm = fmaxf(m0, m1);
    float e0 = fexp2(m0 - mm), e1 = fexp2(m1 - mm);
    float inv = 1.0f / (l0 * e0 + l1 * e1);
    float o0 = (float)op0[r * 64 + lane], o1 = (float)op1[r * 64 + lane];
    int t = g * 16 + r;
    y_buf[((size_t)b * TSEQ + t) * CDIM + h * DH + lane] =
        (__bf16)((o0 * e0 + o1 * e1) * inv);
  }
}

extern "C" void kernel_launch(void* const* d_in, const int* in_sizes, int n_in,
                              void* d_out, int out_size, void* d_ws, size_t ws_size,
                              hipStream_t stream) {
  const float* x      = (const float*)d_in[0];
  const float* W_attn = (const float*)d_in[1];
  const float* b_attn = (const float*)d_in[2];
  const float* W_proj = (const float*)d_in[3];
  const float* b_proj = (const float*)d_in[4];
  float* out = (float*)d_out;
  char* ws = (char*)d_ws;
  const size_t MB = (size_t)1 << 20;
  __bf16* xb  = (__bf16*)(ws + 0 * MB);   // dead after qkv gemm; ml_part overlays it
  __bf16* wab = (__bf16*)(ws + 8 * MB);
  __bf16* wpb = (__bf16*)(ws + 14 * MB);
  __bf16* qbf = (__bf16*)(ws + 16 * MB);
  __bf16* kbf = (__bf16*)(ws + 24 * MB);
  __bf16* vtb = (__bf16*)(ws + 32 * MB);
  __bf16* yb  = (__bf16*)(ws + 40 * MB);
  float*  mlp = (float*)(ws + 0 * MB);    // 1 MB, overlays dead xb
  __bf16* opart = (__bf16*)d_out;         // 16 MB scratch; proj overwrites after

  cvt_bf16<<<2048, 256, 0, stream>>>(x, xb, 524288);
  cvt_bf16<<<1536, 256, 0, stream>>>(W_attn, wab, 393216);
  cvt_bf16<<<512, 256, 0, stream>>>(W_proj, wpb, 131072);

  gemm_bt<1><<<dim3(24, 32), 256, 0, stream>>>(xb, wab, b_attn, nullptr,
                                               qbf, kbf, vtb, 4096, 3072, 1024);
  attn_fwd<<<dim3(32, 32), 256, 0, stream>>>(qbf, kbf, vtb, opart, mlp);
  attn_combine<<<1024, 256, 0, stream>>>(opart, mlp, yb);
  gemm_bt<0><<<dim3(8, 32), 256, 0, stream>>>(yb, wpb, b_proj, out,
                                              nullptr, nullptr, nullptr, 4096, 1024, 1024);
}

// Round 9
// 179.674 us; speedup vs baseline: 1.1719x; 1.1719x over previous
//
#include <hip/hip_runtime.h>

typedef __bf16 bf16x8 __attribute__((ext_vector_type(8)));
typedef __bf16 bf16x4 __attribute__((ext_vector_type(4)));
typedef float  f32x4  __attribute__((ext_vector_type(4)));
typedef float  f32x16 __attribute__((ext_vector_type(16)));

#define TSEQ 2048
#define CDIM 1024
#define NHEAD 16
#define DH 64
#define SCALE2 0.1803368801111137f  // 0.125 * log2(e)

__device__ __forceinline__ void gl_lds16(const void* g, void* l) {
  __builtin_amdgcn_global_load_lds(
      (const __attribute__((address_space(1))) unsigned int*)g,
      (__attribute__((address_space(3))) unsigned int*)l, 16, 0, 0);
}

__device__ __forceinline__ float fexp2(float x) { return __builtin_amdgcn_exp2f(x); }

// v_cvt_pk_bf16_f32: dst.lo16 = bf16(a), dst.hi16 = bf16(b)
__device__ __forceinline__ unsigned cvtpk(float a, float b) {
  unsigned r;
  asm("v_cvt_pk_bf16_f32 %0, %1, %2" : "=v"(r) : "v"(a), "v"(b));
  return r;
}
// v_permlane32_swap_b32: after, x = [x_lanes0-31, y_lanes0-31], y = [x_lanes32-63, y_lanes32-63]
__device__ __forceinline__ void permswap(unsigned& x, unsigned& y) {
  asm("v_permlane32_swap_b32 %0, %1" : "+v"(x), "+v"(y));
}

// ---------------- fp32 -> bf16 conversion (vectorized) ----------------
__global__ __launch_bounds__(256) void cvt_bf16(const float* __restrict__ in,
                                                __bf16* __restrict__ out, int n8) {
  int i = blockIdx.x * 256 + threadIdx.x;
  if (i >= n8) return;
  const float4* p = (const float4*)(in + (size_t)i * 8);
  float4 a = p[0], b = p[1];
  bf16x8 r;
  r[0] = (__bf16)a.x; r[1] = (__bf16)a.y; r[2] = (__bf16)a.z; r[3] = (__bf16)a.w;
  r[4] = (__bf16)b.x; r[5] = (__bf16)b.y; r[6] = (__bf16)b.z; r[7] = (__bf16)b.w;
  *(bf16x8*)(out + (size_t)i * 8) = r;
}

// ---------------- bf16 GEMM (m97-style): out[M,N] = A[M,K]*Bw[N,K]^T + bias --------
// EPI=1 scatters qkv; q is PRE-SCALED by 0.125*log2e.
template <int EPI>
__global__ __launch_bounds__(256) void gemm_bt(
    const __bf16* __restrict__ A, const __bf16* __restrict__ Bw,
    const float* __restrict__ bias, float* __restrict__ outf,
    __bf16* __restrict__ q_buf, __bf16* __restrict__ k_buf,
    __bf16* __restrict__ vT_buf, int M, int N, int K) {
  __shared__ alignas(16) __bf16 lda[128 * 64];
  __shared__ alignas(16) __bf16 ldb[128 * 64];
  const int tid = threadIdx.x;
  const int lane = tid & 63, wid = tid >> 6;
  const int wm = wid >> 1, wn = wid & 1;
  const int row0 = blockIdx.y * 128, col0 = blockIdx.x * 128;
  f32x4 acc[4][4] = {};

  const int srow = lane >> 3;
  const int scb = (lane & 7) * 16;

  for (int k0 = 0; k0 < K; k0 += 64) {
#pragma unroll
    for (int j = 0; j < 4; ++j) {
      int blk = j * 4 + wid;
      int r = blk * 8 + srow;
      char* la = (char*)lda + blk * 1024;
      char* lb = (char*)ldb + blk * 1024;
      gl_lds16((const char*)(A + (size_t)(row0 + r) * K + k0) + scb, la);
      gl_lds16((const char*)(Bw + (size_t)(col0 + r) * K + k0) + scb, lb);
    }
    __syncthreads();
#pragma unroll
    for (int kk = 0; kk < 2; ++kk) {
      bf16x8 af[4], bfr[4];
#pragma unroll
      for (int m = 0; m < 4; ++m)
        af[m] = *(const bf16x8*)&lda[(wm * 64 + m * 16 + (lane & 15)) * 64 + kk * 32 + (lane >> 4) * 8];
#pragma unroll
      for (int n = 0; n < 4; ++n)
        bfr[n] = *(const bf16x8*)&ldb[(wn * 64 + n * 16 + (lane & 15)) * 64 + kk * 32 + (lane >> 4) * 8];
#pragma unroll
      for (int m = 0; m < 4; ++m)
#pragma unroll
        for (int n = 0; n < 4; ++n)
          acc[m][n] = __builtin_amdgcn_mfma_f32_16x16x32_bf16(af[m], bfr[n], acc[m][n], 0, 0, 0);
    }
    __syncthreads();
  }
#pragma unroll
  for (int m = 0; m < 4; ++m) {
#pragma unroll
    for (int n = 0; n < 4; ++n) {
#pragma unroll
      for (int i = 0; i < 4; ++i) {
        int r = row0 + wm * 64 + m * 16 + (lane >> 4) * 4 + i;
        int c = col0 + wn * 64 + n * 16 + (lane & 15);
        float v = acc[m][n][i] + bias[c];
        if (EPI == 0) {
          outf[(size_t)r * N + c] = v;
        } else {
          int bb = r >> 11, t = r & 2047;
          int sec = c >> 10, cc = c & 1023;
          int hh = cc >> 6, d = cc & 63;
          size_t bh = (size_t)bb * NHEAD + hh;
          if (sec == 0)      q_buf[(bh * TSEQ + (size_t)t) * DH + d] = (__bf16)(v * SCALE2);
          else if (sec == 1) k_buf[(bh * TSEQ + (size_t)t) * DH + d] = (__bf16)v;
          else               vT_buf[(bh * DH + (size_t)d) * TSEQ + t] = (__bf16)v;
        }
      }
    }
  }
}

// ---------------- flash attention: swapped-operand 32x32x16, in-register softmax ----
// 1 wave = 32 q-rows (chunk c). S^T = mfma(A=K, B=Q): lane (hi=lane>>5, lq=lane&31)
// owns q-row (c*32+lq), S values at k = kt + (reg&3)+8*(reg>>2)+4*hi. Softmax fully
// in-lane (+1 shfl_xor 32). P -> B-frag via cvt_pk + permlane32_swap (T12). PV:
// O^T = mfma(A=V^T rows, B=P^T) -- vT_buf layout feeds A directly. T13 defer-max.
// KVBLK=32: only subtile j==c needs the causal mask. Grid (bh=32, 64) heavy-first.
__global__ __launch_bounds__(64) void attn_fwd(
    const __bf16* __restrict__ q_buf, const __bf16* __restrict__ k_buf,
    const __bf16* __restrict__ vT_buf, __bf16* __restrict__ y_buf) {
  const int lane = threadIdx.x;
  const int lq = lane & 31;
  const int hi = lane >> 5;
  const int bh = blockIdx.x;
  const int c = 63 - (int)blockIdx.y;  // heavy chunks dispatched first
  const int b = bh >> 4, h = bh & 15;
  const float slope2 = exp2f(-0.5f * (float)(h + 1)) * 1.44269504f;
  const __bf16* qp = q_buf + (size_t)bh * TSEQ * DH;
  const __bf16* kp = k_buf + (size_t)bh * TSEQ * DH;
  const __bf16* vp = vT_buf + (size_t)bh * DH * TSEQ;
  const int q0 = c * 32;

  // Q B-frags (col=lq=q, contraction dh = m*16 + hi*8 + j)
  bf16x8 qf[4];
#pragma unroll
  for (int m = 0; m < 4; ++m)
    qf[m] = *(const bf16x8*)&qp[(size_t)(q0 + lq) * DH + m * 16 + hi * 8];

  // per-reg ALiBi premultiplied k-offsets: pk_[r] = slope2 * koff(r,hi)
  float pk_[16];
#pragma unroll
  for (int r = 0; r < 16; ++r)
    pk_[r] = slope2 * (float)((r & 3) + 8 * (r >> 2) + 4 * hi);

  f32x16 o0 = {}, o1 = {};  // O^T: d = (reg&3)+8*(reg>>2)+4*hi (+32 for o1), col q=lq
  float m_r = -__builtin_inff(), l_r = 0.f;

  // K A-frags for subtile 0 (row=lq=k, contraction dh)
  bf16x8 kf[4];
#pragma unroll
  for (int m = 0; m < 4; ++m)
    kf[m] = *(const bf16x8*)&kp[(size_t)lq * DH + m * 16 + hi * 8];

  for (int j = 0; j <= c; ++j) {
    const int kt = j * 32;
    // V A-frags for this subtile (rows d = lq / 32+lq, contraction k)
    bf16x8 va0[2], va1[2];
#pragma unroll
    for (int kh = 0; kh < 2; ++kh) {
      va0[kh] = *(const bf16x8*)&vp[(size_t)lq * TSEQ + kt + kh * 16 + hi * 8];
      va1[kh] = *(const bf16x8*)&vp[(size_t)(32 + lq) * TSEQ + kt + kh * 16 + hi * 8];
    }
    // prefetch next K subtile
    bf16x8 kn[4];
    if (j < c) {
#pragma unroll
      for (int m = 0; m < 4; ++m)
        kn[m] = *(const bf16x8*)&kp[(size_t)(kt + 32 + lq) * DH + m * 16 + hi * 8];
    }
    // S^T = K Q^T (chained over dh)
    f32x16 s = {};
#pragma unroll
    for (int m = 0; m < 4; ++m)
      s = __builtin_amdgcn_mfma_f32_32x32x16_bf16(kf[m], qf[m], s, 0, 0, 0);
    // ALiBi column bias (row term is softmax-invariant, dropped)
    const float ktb = slope2 * (float)kt;
#pragma unroll
    for (int r = 0; r < 16; ++r) s[r] = (s[r] + ktb) + pk_[r];
    // causal mask: only the diagonal subtile (kt == q0), k>q <=> koff>lq
    if (j == c) {
#pragma unroll
      for (int r = 0; r < 16; ++r) {
        int kof = (r & 3) + 8 * (r >> 2) + 4 * hi;
        if (kof > lq) s[r] = -__builtin_inff();
      }
    }
    // row max (in-lane + cross-hi)
    float px = s[0];
#pragma unroll
    for (int r = 1; r < 16; ++r) px = fmaxf(px, s[r]);
    px = fmaxf(px, __shfl_xor(px, 32, 64));
    // defer-max (T13, THR=8): skip rescale while max growth bounded
    if (!__all(px <= m_r + 8.f)) {
      float mn = fmaxf(m_r, px);
      float corr = fexp2(m_r - mn);
      m_r = mn;
      l_r *= corr;
#pragma unroll
      for (int r = 0; r < 16; ++r) { o0[r] *= corr; o1[r] *= corr; }
    }
    // P = exp2(S - m), row sum
    float rs = 0.f;
#pragma unroll
    for (int r = 0; r < 16; ++r) {
      s[r] = fexp2(s[r] - m_r);
      rs += s[r];
    }
    rs += __shfl_xor(rs, 32, 64);
    l_r += rs;
    // pack P -> two B-frags (contraction k halves 0..15, 16..31)
    bf16x8 pb[2];
#pragma unroll
    for (int kh = 0; kh < 2; ++kh) {
      const int bq = kh * 8;
      unsigned w0 = cvtpk(s[bq + 0], s[bq + 1]);
      unsigned w1 = cvtpk(s[bq + 2], s[bq + 3]);
      unsigned w2 = cvtpk(s[bq + 4], s[bq + 5]);
      unsigned w3 = cvtpk(s[bq + 6], s[bq + 7]);
      permswap(w0, w2);  // w0 = word0 (k 0-1|8-9), w2 = word2 (k 4-5|12-13)
      permswap(w1, w3);  // w1 = word1, w3 = word3
      union { unsigned u[4]; bf16x8 v; } pbu;
      pbu.u[0] = w0; pbu.u[1] = w1; pbu.u[2] = w2; pbu.u[3] = w3;
      pb[kh] = pbu.v;
    }
    // O^T += V^T P^T
    o0 = __builtin_amdgcn_mfma_f32_32x32x16_bf16(va0[0], pb[0], o0, 0, 0, 0);
    o0 = __builtin_amdgcn_mfma_f32_32x32x16_bf16(va0[1], pb[1], o0, 0, 0, 0);
    o1 = __builtin_amdgcn_mfma_f32_32x32x16_bf16(va1[0], pb[0], o1, 0, 0, 0);
    o1 = __builtin_amdgcn_mfma_f32_32x32x16_bf16(va1[1], pb[1], o1, 0, 0, 0);
    if (j < c) {
#pragma unroll
      for (int m = 0; m < 4; ++m) kf[m] = kn[m];
    }
  }
  // normalize + write y[b][t][h*64+d]; lane owns row t = q0+lq entirely
  const float inv = 1.0f / l_r;
  __bf16* yb = y_buf + ((size_t)b * TSEQ + q0 + lq) * CDIM + h * DH;
#pragma unroll
  for (int g = 0; g < 4; ++g) {
    bf16x4 v0, v1;
#pragma unroll
    for (int e = 0; e < 4; ++e) {
      v0[e] = (__bf16)(o0[4 * g + e] * inv);
      v1[e] = (__bf16)(o1[4 * g + e] * inv);
    }
    *(bf16x4*)&yb[8 * g + 4 * hi] = v0;        // d = 8g+4hi+e
    *(bf16x4*)&yb[32 + 8 * g + 4 * hi] = v1;   // d = 32+8g+4hi+e
  }
}

extern "C" void kernel_launch(void* const* d_in, const int* in_sizes, int n_in,
                              void* d_out, int out_size, void* d_ws, size_t ws_size,
                              hipStream_t stream) {
  const float* x      = (const float*)d_in[0];
  const float* W_attn = (const float*)d_in[1];
  const float* b_attn = (const float*)d_in[2];
  const float* W_proj = (const float*)d_in[3];
  const float* b_proj = (const float*)d_in[4];
  float* out = (float*)d_out;
  char* ws = (char*)d_ws;
  const size_t MB = (size_t)1 << 20;
  __bf16* xb  = (__bf16*)(ws + 0 * MB);
  __bf16* wab = (__bf16*)(ws + 8 * MB);
  __bf16* wpb = (__bf16*)(ws + 14 * MB);
  __bf16* qbf = (__bf16*)(ws + 16 * MB);
  __bf16* kbf = (__bf16*)(ws + 24 * MB);
  __bf16* vtb = (__bf16*)(ws + 32 * MB);
  __bf16* yb  = (__bf16*)(ws + 40 * MB);

  cvt_bf16<<<2048, 256, 0, stream>>>(x, xb, 524288);
  cvt_bf16<<<1536, 256, 0, stream>>>(W_attn, wab, 393216);
  cvt_bf16<<<512, 256, 0, stream>>>(W_proj, wpb, 131072);

  gemm_bt<1><<<dim3(24, 32), 256, 0, stream>>>(xb, wab, b_attn, nullptr,
                                               qbf, kbf, vtb, 4096, 3072, 1024);
  attn_fwd<<<dim3(32, 64), 64, 0, stream>>>(qbf, kbf, vtb, yb);
  gemm_bt<0><<<dim3(8, 32), 256, 0, stream>>>(yb, wpb, b_proj, out,
                                              nullptr, nullptr, nullptr, 4096, 1024, 1024);
}

// Round 10
// 167.702 us; speedup vs baseline: 1.2556x; 1.0714x over previous
//
#include <hip/hip_runtime.h>

typedef __bf16 bf16x8 __attribute__((ext_vector_type(8)));
typedef __bf16 bf16x4 __attribute__((ext_vector_type(4)));
typedef float  f32x4  __attribute__((ext_vector_type(4)));
typedef float  f32x16 __attribute__((ext_vector_type(16)));

#define TSEQ 2048
#define CDIM 1024
#define NHEAD 16
#define DH 64
#define SCALE2 0.1803368801111137f  // 0.125 * log2(e)

__device__ __forceinline__ void gl_lds16(const void* g, void* l) {
  __builtin_amdgcn_global_load_lds(
      (const __attribute__((address_space(1))) unsigned int*)g,
      (__attribute__((address_space(3))) unsigned int*)l, 16, 0, 0);
}

__device__ __forceinline__ float fexp2(float x) { return __builtin_amdgcn_exp2f(x); }

__device__ __forceinline__ unsigned cvtpk(float a, float b) {
  unsigned r;
  asm("v_cvt_pk_bf16_f32 %0, %1, %2" : "=v"(r) : "v"(a), "v"(b));
  return r;
}
__device__ __forceinline__ void permswap(unsigned& x, unsigned& y) {
  asm("v_permlane32_swap_b32 %0, %1" : "+v"(x), "+v"(y));
}

__device__ __forceinline__ float tmax16(const f32x16& s) {
  float a0 = fmaxf(s[0], s[1]), a1 = fmaxf(s[2], s[3]);
  float a2 = fmaxf(s[4], s[5]), a3 = fmaxf(s[6], s[7]);
  float a4 = fmaxf(s[8], s[9]), a5 = fmaxf(s[10], s[11]);
  float a6 = fmaxf(s[12], s[13]), a7 = fmaxf(s[14], s[15]);
  float b0 = fmaxf(a0, a1), b1 = fmaxf(a2, a3);
  float b2 = fmaxf(a4, a5), b3 = fmaxf(a6, a7);
  return fmaxf(fmaxf(b0, b1), fmaxf(b2, b3));
}
__device__ __forceinline__ float tsum16(const f32x16& s) {
  float a0 = s[0] + s[1], a1 = s[2] + s[3], a2 = s[4] + s[5], a3 = s[6] + s[7];
  float a4 = s[8] + s[9], a5 = s[10] + s[11], a6 = s[12] + s[13], a7 = s[14] + s[15];
  float b0 = a0 + a1, b1 = a2 + a3, b2 = a4 + a5, b3 = a6 + a7;
  return (b0 + b1) + (b2 + b3);
}

// ---------------- fp32 -> bf16 conversion (vectorized) ----------------
__global__ __launch_bounds__(256) void cvt_bf16(const float* __restrict__ in,
                                                __bf16* __restrict__ out, int n8) {
  int i = blockIdx.x * 256 + threadIdx.x;
  if (i >= n8) return;
  const float4* p = (const float4*)(in + (size_t)i * 8);
  float4 a = p[0], b = p[1];
  bf16x8 r;
  r[0] = (__bf16)a.x; r[1] = (__bf16)a.y; r[2] = (__bf16)a.z; r[3] = (__bf16)a.w;
  r[4] = (__bf16)b.x; r[5] = (__bf16)b.y; r[6] = (__bf16)b.z; r[7] = (__bf16)b.w;
  *(bf16x8*)(out + (size_t)i * 8) = r;
}

// ---------------- bf16 GEMM (m97-style): out[M,N] = A[M,K]*Bw[N,K]^T + bias --------
// EPI=1 scatters qkv; q is PRE-SCALED by 0.125*log2e.
template <int EPI>
__global__ __launch_bounds__(256) void gemm_bt(
    const __bf16* __restrict__ A, const __bf16* __restrict__ Bw,
    const float* __restrict__ bias, float* __restrict__ outf,
    __bf16* __restrict__ q_buf, __bf16* __restrict__ k_buf,
    __bf16* __restrict__ vT_buf, int M, int N, int K) {
  __shared__ alignas(16) __bf16 lda[128 * 64];
  __shared__ alignas(16) __bf16 ldb[128 * 64];
  const int tid = threadIdx.x;
  const int lane = tid & 63, wid = tid >> 6;
  const int wm = wid >> 1, wn = wid & 1;
  const int row0 = blockIdx.y * 128, col0 = blockIdx.x * 128;
  f32x4 acc[4][4] = {};

  const int srow = lane >> 3;
  const int scb = (lane & 7) * 16;

  for (int k0 = 0; k0 < K; k0 += 64) {
#pragma unroll
    for (int j = 0; j < 4; ++j) {
      int blk = j * 4 + wid;
      int r = blk * 8 + srow;
      char* la = (char*)lda + blk * 1024;
      char* lb = (char*)ldb + blk * 1024;
      gl_lds16((const char*)(A + (size_t)(row0 + r) * K + k0) + scb, la);
      gl_lds16((const char*)(Bw + (size_t)(col0 + r) * K + k0) + scb, lb);
    }
    __syncthreads();
#pragma unroll
    for (int kk = 0; kk < 2; ++kk) {
      bf16x8 af[4], bfr[4];
#pragma unroll
      for (int m = 0; m < 4; ++m)
        af[m] = *(const bf16x8*)&lda[(wm * 64 + m * 16 + (lane & 15)) * 64 + kk * 32 + (lane >> 4) * 8];
#pragma unroll
      for (int n = 0; n < 4; ++n)
        bfr[n] = *(const bf16x8*)&ldb[(wn * 64 + n * 16 + (lane & 15)) * 64 + kk * 32 + (lane >> 4) * 8];
#pragma unroll
      for (int m = 0; m < 4; ++m)
#pragma unroll
        for (int n = 0; n < 4; ++n)
          acc[m][n] = __builtin_amdgcn_mfma_f32_16x16x32_bf16(af[m], bfr[n], acc[m][n], 0, 0, 0);
    }
    __syncthreads();
  }
#pragma unroll
  for (int m = 0; m < 4; ++m) {
#pragma unroll
    for (int n = 0; n < 4; ++n) {
#pragma unroll
      for (int i = 0; i < 4; ++i) {
        int r = row0 + wm * 64 + m * 16 + (lane >> 4) * 4 + i;
        int c = col0 + wn * 64 + n * 16 + (lane & 15);
        float v = acc[m][n][i] + bias[c];
        if (EPI == 0) {
          outf[(size_t)r * N + c] = v;
        } else {
          int bb = r >> 11, t = r & 2047;
          int sec = c >> 10, cc = c & 1023;
          int hh = cc >> 6, d = cc & 63;
          size_t bh = (size_t)bb * NHEAD + hh;
          if (sec == 0)      q_buf[(bh * TSEQ + (size_t)t) * DH + d] = (__bf16)(v * SCALE2);
          else if (sec == 1) k_buf[(bh * TSEQ + (size_t)t) * DH + d] = (__bf16)v;
          else               vT_buf[(bh * DH + (size_t)d) * TSEQ + t] = (__bf16)v;
        }
      }
    }
  }
}

// ---------------- attention softmax+PV for one chunk-tile (in-register) ----------
__device__ __forceinline__ void softmax_pv(
    f32x16& s, bool domask, float ktb, const float* pk_, int lq, int hi,
    float& m_r, float& l_r, f32x16& o0, f32x16& o1,
    const bf16x8* va0, const bf16x8* va1) {
#pragma unroll
  for (int r = 0; r < 16; ++r) s[r] += pk_[r];
  if (domask) {
#pragma unroll
    for (int r = 0; r < 16; ++r) {
      int kof = (r & 3) + 8 * (r >> 2) + 4 * hi;
      if (kof > lq) s[r] = -__builtin_inff();
    }
  }
  float msh = m_r - ktb;  // shifted running max (ktb uniform within tile)
  float px = tmax16(s);
  px = fmaxf(px, __shfl_xor(px, 32, 64));  // row max across hi halves (always finite)
  if (!__all(px <= msh + 8.f)) {           // defer-max (T13)
    float mn = fmaxf(msh, px);
    float corr = fexp2(msh - mn);
    msh = mn;
    m_r = mn + ktb;
    l_r *= corr;
#pragma unroll
    for (int r = 0; r < 16; ++r) { o0[r] *= corr; o1[r] *= corr; }
  }
#pragma unroll
  for (int r = 0; r < 16; ++r) s[r] = fexp2(s[r] - msh);
  float rs = tsum16(s);
  rs += __shfl_xor(rs, 32, 64);
  l_r += rs;
  // pack P -> two B-frags (contraction k halves 0..15, 16..31)
  bf16x8 pb[2];
#pragma unroll
  for (int kh = 0; kh < 2; ++kh) {
    const int bq = kh * 8;
    unsigned w0 = cvtpk(s[bq + 0], s[bq + 1]);
    unsigned w1 = cvtpk(s[bq + 2], s[bq + 3]);
    unsigned w2 = cvtpk(s[bq + 4], s[bq + 5]);
    unsigned w3 = cvtpk(s[bq + 6], s[bq + 7]);
    permswap(w0, w2);
    permswap(w1, w3);
    union { unsigned u[4]; bf16x8 v; } pbu;
    pbu.u[0] = w0; pbu.u[1] = w1; pbu.u[2] = w2; pbu.u[3] = w3;
    pb[kh] = pbu.v;
  }
  o0 = __builtin_amdgcn_mfma_f32_32x32x16_bf16(va0[0], pb[0], o0, 0, 0, 0);
  o0 = __builtin_amdgcn_mfma_f32_32x32x16_bf16(va0[1], pb[1], o0, 0, 0, 0);
  o1 = __builtin_amdgcn_mfma_f32_32x32x16_bf16(va1[0], pb[0], o1, 0, 0, 0);
  o1 = __builtin_amdgcn_mfma_f32_32x32x16_bf16(va1[1], pb[1], o1, 0, 0, 0);
}

// ---------------- flash attention: swapped 32x32, paired chunks, split-K parity ----
// 1 wave; chunks {cH=63-wv (heavy), cL=wv (light)} share K/V loads; tiles j=hf,hf+2..
// Partials (unnormalized O bf16, m/l fp32) out; combine merges the two parities.
__global__ __launch_bounds__(64) void attn_fwd(
    const __bf16* __restrict__ q_buf, const __bf16* __restrict__ k_buf,
    const __bf16* __restrict__ vT_buf, __bf16* __restrict__ o_part,
    float* __restrict__ ml_part) {
  const int lane = threadIdx.x;
  const int lq = lane & 31;
  const int hi = lane >> 5;
  const int bh = blockIdx.x;
  const int wv = blockIdx.y >> 1;   // y=0 first -> heaviest pair first
  const int hf = blockIdx.y & 1;
  const int h = bh & 15;
  const int cH = 63 - wv, cL = wv;
  const float slope2 = exp2f(-0.5f * (float)(h + 1)) * 1.44269504f;
  const __bf16* qp = q_buf + (size_t)bh * TSEQ * DH;
  const __bf16* kp = k_buf + (size_t)bh * TSEQ * DH;
  const __bf16* vp = vT_buf + (size_t)bh * DH * TSEQ;

  bf16x8 qfH[4], qfL[4];
#pragma unroll
  for (int m = 0; m < 4; ++m) {
    qfH[m] = *(const bf16x8*)&qp[(size_t)(cH * 32 + lq) * DH + m * 16 + hi * 8];
    qfL[m] = *(const bf16x8*)&qp[(size_t)(cL * 32 + lq) * DH + m * 16 + hi * 8];
  }
  float pk_[16];
#pragma unroll
  for (int r = 0; r < 16; ++r)
    pk_[r] = slope2 * (float)((r & 3) + 8 * (r >> 2) + 4 * hi);

  f32x16 oH0 = {}, oH1 = {}, oL0 = {}, oL1 = {};
  float mH = -__builtin_inff(), lH = 0.f, mL = -__builtin_inff(), lL = 0.f;

  bf16x8 kf[4];
#pragma unroll
  for (int m = 0; m < 4; ++m)
    kf[m] = *(const bf16x8*)&kp[(size_t)(hf * 32 + lq) * DH + m * 16 + hi * 8];

  for (int j = hf; j <= cH; j += 2) {
    const int kt = j * 32;
    bf16x8 va0[2], va1[2];
#pragma unroll
    for (int kh = 0; kh < 2; ++kh) {
      va0[kh] = *(const bf16x8*)&vp[(size_t)lq * TSEQ + kt + kh * 16 + hi * 8];
      va1[kh] = *(const bf16x8*)&vp[(size_t)(32 + lq) * TSEQ + kt + kh * 16 + hi * 8];
    }
    bf16x8 kn[4];
    const bool pre = (j + 2 <= cH);
    if (pre) {
#pragma unroll
      for (int m = 0; m < 4; ++m)
        kn[m] = *(const bf16x8*)&kp[(size_t)(kt + 64 + lq) * DH + m * 16 + hi * 8];
    }
    // issue both S MFMAs up front: S_L executes while softmax_H VALU runs
    f32x16 sH = {};
#pragma unroll
    for (int m = 0; m < 4; ++m)
      sH = __builtin_amdgcn_mfma_f32_32x32x16_bf16(kf[m], qfH[m], sH, 0, 0, 0);
    const bool lact = (j <= cL);
    f32x16 sL = {};
    if (lact) {
#pragma unroll
      for (int m = 0; m < 4; ++m)
        sL = __builtin_amdgcn_mfma_f32_32x32x16_bf16(kf[m], qfL[m], sL, 0, 0, 0);
    }
    const float ktb = slope2 * (float)kt;
    softmax_pv(sH, j == cH, ktb, pk_, lq, hi, mH, lH, oH0, oH1, va0, va1);
    if (lact)
      softmax_pv(sL, j == cL, ktb, pk_, lq, hi, mL, lL, oL0, oL1, va0, va1);
    if (pre) {
#pragma unroll
      for (int m = 0; m < 4; ++m) kf[m] = kn[m];
    }
  }

  // write partials: slot = hf*2048 + bh*64 + c ; o rows 32x64 bf16, ml 32m+32l f32
#pragma unroll
  for (int g2 = 0; g2 < 2; ++g2) {
    const int c = g2 ? cL : cH;
    const f32x16& a0 = g2 ? oL0 : oH0;
    const f32x16& a1 = g2 ? oL1 : oH1;
    const float mv = g2 ? mL : mH;
    const float lv = g2 ? lL : lH;
    const size_t slot = (size_t)hf * 2048 + (size_t)bh * 64 + c;
    __bf16* op = o_part + slot * 2048 + (size_t)lq * 64;
#pragma unroll
    for (int g = 0; g < 4; ++g) {
      bf16x4 v0, v1;
#pragma unroll
      for (int e = 0; e < 4; ++e) {
        v0[e] = (__bf16)a0[4 * g + e];
        v1[e] = (__bf16)a1[4 * g + e];
      }
      *(bf16x4*)&op[8 * g + 4 * hi] = v0;
      *(bf16x4*)&op[32 + 8 * g + 4 * hi] = v1;
    }
    if (hi == 0) {
      ml_part[slot * 64 + lq] = mv;
      ml_part[slot * 64 + 32 + lq] = lv;
    }
  }
}

// ---------------- combine the two parity halves ----------------
__global__ __launch_bounds__(256) void attn_combine(
    const __bf16* __restrict__ o_part, const float* __restrict__ ml,
    __bf16* __restrict__ y_buf) {
  const int tid = threadIdx.x;
  const int t8 = tid & 7, rloc = tid >> 3;
  const int row = blockIdx.x * 32 + rloc;   // 0..65535
  const int slot = row >> 5, lq = row & 31; // slot = bh*64 + c
  const int bh = slot >> 6, cc = slot & 63;
  const int b = bh >> 4, h = bh & 15;
  float m0 = ml[(size_t)slot * 64 + lq], l0 = ml[(size_t)slot * 64 + 32 + lq];
  float m1 = ml[(size_t)(2048 + slot) * 64 + lq], l1 = ml[(size_t)(2048 + slot) * 64 + 32 + lq];
  float mm = fmaxf(m0, m1);
  float e0 = fexp2(m0 - mm), e1 = fexp2(m1 - mm);
  float inv = 1.0f / (l0 * e0 + l1 * e1);
  float s0 = e0 * inv, s1 = e1 * inv;
  bf16x8 a = *(const bf16x8*)(o_part + (size_t)slot * 2048 + (size_t)lq * 64 + t8 * 8);
  bf16x8 c2 = *(const bf16x8*)(o_part + (size_t)(2048 + slot) * 2048 + (size_t)lq * 64 + t8 * 8);
  bf16x8 r;
#pragma unroll
  for (int e = 0; e < 8; ++e)
    r[e] = (__bf16)((float)a[e] * s0 + (float)c2[e] * s1);
  const int t = cc * 32 + lq;
  *(bf16x8*)&y_buf[((size_t)b * TSEQ + t) * CDIM + h * DH + t8 * 8] = r;
}

extern "C" void kernel_launch(void* const* d_in, const int* in_sizes, int n_in,
                              void* d_out, int out_size, void* d_ws, size_t ws_size,
                              hipStream_t stream) {
  const float* x      = (const float*)d_in[0];
  const float* W_attn = (const float*)d_in[1];
  const float* b_attn = (const float*)d_in[2];
  const float* W_proj = (const float*)d_in[3];
  const float* b_proj = (const float*)d_in[4];
  float* out = (float*)d_out;
  char* ws = (char*)d_ws;
  const size_t MB = (size_t)1 << 20;
  __bf16* xb  = (__bf16*)(ws + 0 * MB);   // dead after qkv gemm; ml_part overlays it
  __bf16* wab = (__bf16*)(ws + 8 * MB);
  __bf16* wpb = (__bf16*)(ws + 14 * MB);
  __bf16* qbf = (__bf16*)(ws + 16 * MB);
  __bf16* kbf = (__bf16*)(ws + 24 * MB);
  __bf16* vtb = (__bf16*)(ws + 32 * MB);
  __bf16* yb  = (__bf16*)(ws + 40 * MB);
  float*  mlp = (float*)(ws + 0 * MB);    // 1 MB over dead xb
  __bf16* opart = (__bf16*)d_out;         // 16.78 MB scratch; combine reads, proj overwrites

  cvt_bf16<<<2048, 256, 0, stream>>>(x, xb, 524288);
  cvt_bf16<<<1536, 256, 0, stream>>>(W_attn, wab, 393216);
  cvt_bf16<<<512, 256, 0, stream>>>(W_proj, wpb, 131072);

  gemm_bt<1><<<dim3(24, 32), 256, 0, stream>>>(xb, wab, b_attn, nullptr,
                                               qbf, kbf, vtb, 4096, 3072, 1024);
  attn_fwd<<<dim3(32, 64), 64, 0, stream>>>(qbf, kbf, vtb, opart, mlp);
  attn_combine<<<2048, 256, 0, stream>>>(opart, mlp, yb);
  gemm_bt<0><<<dim3(8, 32), 256, 0, stream>>>(yb, wpb, b_proj, out,
                                              nullptr, nullptr, nullptr, 4096, 1024, 1024);
}

// Round 11
// 144.101 us; speedup vs baseline: 1.4612x; 1.1638x over previous
//
#include <hip/hip_runtime.h>

typedef __bf16 bf16x8 __attribute__((ext_vector_type(8)));
typedef __bf16 bf16x4 __attribute__((ext_vector_type(4)));
typedef float  f32x4  __attribute__((ext_vector_type(4)));
typedef float  f32x16 __attribute__((ext_vector_type(16)));

#define TSEQ 2048
#define CDIM 1024
#define NHEAD 16
#define DH 64
#define SCALE2 0.1803368801111137f  // 0.125 * log2(e)

__device__ __forceinline__ void gl_lds16(const void* g, void* l) {
  __builtin_amdgcn_global_load_lds(
      (const __attribute__((address_space(1))) unsigned int*)g,
      (__attribute__((address_space(3))) unsigned int*)l, 16, 0, 0);
}

__device__ __forceinline__ float fexp2(float x) { return __builtin_amdgcn_exp2f(x); }

__device__ __forceinline__ unsigned cvtpk(float a, float b) {
  unsigned r;
  asm("v_cvt_pk_bf16_f32 %0, %1, %2" : "=v"(r) : "v"(a), "v"(b));
  return r;
}
__device__ __forceinline__ void permswap(unsigned& x, unsigned& y) {
  asm("v_permlane32_swap_b32 %0, %1" : "+v"(x), "+v"(y));
}

__device__ __forceinline__ float tmax16(const f32x16& s) {
  float a0 = fmaxf(s[0], s[1]), a1 = fmaxf(s[2], s[3]);
  float a2 = fmaxf(s[4], s[5]), a3 = fmaxf(s[6], s[7]);
  float a4 = fmaxf(s[8], s[9]), a5 = fmaxf(s[10], s[11]);
  float a6 = fmaxf(s[12], s[13]), a7 = fmaxf(s[14], s[15]);
  float b0 = fmaxf(a0, a1), b1 = fmaxf(a2, a3);
  float b2 = fmaxf(a4, a5), b3 = fmaxf(a6, a7);
  return fmaxf(fmaxf(b0, b1), fmaxf(b2, b3));
}
__device__ __forceinline__ float tsum16(const f32x16& s) {
  float a0 = s[0] + s[1], a1 = s[2] + s[3], a2 = s[4] + s[5], a3 = s[6] + s[7];
  float a4 = s[8] + s[9], a5 = s[10] + s[11], a6 = s[12] + s[13], a7 = s[14] + s[15];
  float b0 = a0 + a1, b1 = a2 + a3, b2 = a4 + a5, b3 = a6 + a7;
  return (b0 + b1) + (b2 + b3);
}

// ---------------- fp32 -> bf16 conversion (vectorized) ----------------
__global__ __launch_bounds__(256) void cvt_bf16(const float* __restrict__ in,
                                                __bf16* __restrict__ out, int n8) {
  int i = blockIdx.x * 256 + threadIdx.x;
  if (i >= n8) return;
  const float4* p = (const float4*)(in + (size_t)i * 8);
  float4 a = p[0], b = p[1];
  bf16x8 r;
  r[0] = (__bf16)a.x; r[1] = (__bf16)a.y; r[2] = (__bf16)a.z; r[3] = (__bf16)a.w;
  r[4] = (__bf16)b.x; r[5] = (__bf16)b.y; r[6] = (__bf16)b.z; r[7] = (__bf16)b.w;
  *(bf16x8*)(out + (size_t)i * 8) = r;
}

// ---------------- bf16 GEMM (m97-style + T2 swizzle): out = A*Bw^T + bias --------
// LDS bank-conflict fix (R10: 9.4M conflicts, LDS-pipe saturated): global source is
// pre-swizzled (slot s loads global slot s^(row&7); rule #21 both-sides involution),
// LDS dest stays linear for global_load_lds; ds_reads use slot^(row&7).
// EPI=1 scatters qkv; q is PRE-SCALED by 0.125*log2e.
template <int EPI>
__global__ __launch_bounds__(256) void gemm_bt(
    const __bf16* __restrict__ A, const __bf16* __restrict__ Bw,
    const float* __restrict__ bias, float* __restrict__ outf,
    __bf16* __restrict__ q_buf, __bf16* __restrict__ k_buf,
    __bf16* __restrict__ vT_buf, int M, int N, int K) {
  __shared__ alignas(16) __bf16 lda[128 * 64];
  __shared__ alignas(16) __bf16 ldb[128 * 64];
  const int tid = threadIdx.x;
  const int lane = tid & 63, wid = tid >> 6;
  const int wm = wid >> 1, wn = wid & 1;
  const int row0 = blockIdx.y * 128, col0 = blockIdx.x * 128;
  f32x4 acc[4][4] = {};

  const int srow = lane >> 3;
  // swizzled source slot: lane (r=lane>>3, s=lane&7) fetches global slot s^r
  const int scb = ((lane & 7) ^ (lane >> 3)) * 16;

  for (int k0 = 0; k0 < K; k0 += 64) {
#pragma unroll
    for (int j = 0; j < 4; ++j) {
      int blk = j * 4 + wid;
      int r = blk * 8 + srow;
      char* la = (char*)lda + blk * 1024;
      char* lb = (char*)ldb + blk * 1024;
      gl_lds16((const char*)(A + (size_t)(row0 + r) * K + k0) + scb, la);
      gl_lds16((const char*)(Bw + (size_t)(col0 + r) * K + k0) + scb, lb);
    }
    __syncthreads();
#pragma unroll
    for (int kk = 0; kk < 2; ++kk) {
      // global slot t = kk*4 + (lane>>4) lives at LDS slot t^(row&7); row&7 == lane&7
      const int sl = (((kk << 2) | (lane >> 4)) ^ (lane & 7)) * 16;
      bf16x8 af[4], bfr[4];
#pragma unroll
      for (int m = 0; m < 4; ++m)
        af[m] = *(const bf16x8*)((const char*)lda +
                                 (wm * 64 + m * 16 + (lane & 15)) * 128 + sl);
#pragma unroll
      for (int n = 0; n < 4; ++n)
        bfr[n] = *(const bf16x8*)((const char*)ldb +
                                  (wn * 64 + n * 16 + (lane & 15)) * 128 + sl);
#pragma unroll
      for (int m = 0; m < 4; ++m)
#pragma unroll
        for (int n = 0; n < 4; ++n)
          acc[m][n] = __builtin_amdgcn_mfma_f32_16x16x32_bf16(af[m], bfr[n], acc[m][n], 0, 0, 0);
    }
    __syncthreads();
  }
#pragma unroll
  for (int m = 0; m < 4; ++m) {
#pragma unroll
    for (int n = 0; n < 4; ++n) {
#pragma unroll
      for (int i = 0; i < 4; ++i) {
        int r = row0 + wm * 64 + m * 16 + (lane >> 4) * 4 + i;
        int c = col0 + wn * 64 + n * 16 + (lane & 15);
        float v = acc[m][n][i] + bias[c];
        if (EPI == 0) {
          outf[(size_t)r * N + c] = v;
        } else {
          int bb = r >> 11, t = r & 2047;
          int sec = c >> 10, cc = c & 1023;
          int hh = cc >> 6, d = cc & 63;
          size_t bh = (size_t)bb * NHEAD + hh;
          if (sec == 0)      q_buf[(bh * TSEQ + (size_t)t) * DH + d] = (__bf16)(v * SCALE2);
          else if (sec == 1) k_buf[(bh * TSEQ + (size_t)t) * DH + d] = (__bf16)v;
          else               vT_buf[(bh * DH + (size_t)d) * TSEQ + t] = (__bf16)v;
        }
      }
    }
  }
}

// ---------------- attention softmax+PV for one chunk-tile (in-register) ----------
__device__ __forceinline__ void softmax_pv(
    f32x16& s, bool domask, float ktb, const float* pk_, int lq, int hi,
    float& m_r, float& l_r, f32x16& o0, f32x16& o1,
    const bf16x8* va0, const bf16x8* va1) {
#pragma unroll
  for (int r = 0; r < 16; ++r) s[r] += pk_[r];
  if (domask) {
#pragma unroll
    for (int r = 0; r < 16; ++r) {
      int kof = (r & 3) + 8 * (r >> 2) + 4 * hi;
      if (kof > lq) s[r] = -__builtin_inff();
    }
  }
  float msh = m_r - ktb;  // shifted running max (ktb uniform within tile)
  float px = tmax16(s);
  px = fmaxf(px, __shfl_xor(px, 32, 64));
  if (!__all(px <= msh + 8.f)) {           // defer-max (T13)
    float mn = fmaxf(msh, px);
    float corr = fexp2(msh - mn);
    msh = mn;
    m_r = mn + ktb;
    l_r *= corr;
#pragma unroll
    for (int r = 0; r < 16; ++r) { o0[r] *= corr; o1[r] *= corr; }
  }
#pragma unroll
  for (int r = 0; r < 16; ++r) s[r] = fexp2(s[r] - msh);
  float rs = tsum16(s);
  rs += __shfl_xor(rs, 32, 64);
  l_r += rs;
  bf16x8 pb[2];
#pragma unroll
  for (int kh = 0; kh < 2; ++kh) {
    const int bq = kh * 8;
    unsigned w0 = cvtpk(s[bq + 0], s[bq + 1]);
    unsigned w1 = cvtpk(s[bq + 2], s[bq + 3]);
    unsigned w2 = cvtpk(s[bq + 4], s[bq + 5]);
    unsigned w3 = cvtpk(s[bq + 6], s[bq + 7]);
    permswap(w0, w2);
    permswap(w1, w3);
    union { unsigned u[4]; bf16x8 v; } pbu;
    pbu.u[0] = w0; pbu.u[1] = w1; pbu.u[2] = w2; pbu.u[3] = w3;
    pb[kh] = pbu.v;
  }
  o0 = __builtin_amdgcn_mfma_f32_32x32x16_bf16(va0[0], pb[0], o0, 0, 0, 0);
  o0 = __builtin_amdgcn_mfma_f32_32x32x16_bf16(va0[1], pb[1], o0, 0, 0, 0);
  o1 = __builtin_amdgcn_mfma_f32_32x32x16_bf16(va1[0], pb[0], o1, 0, 0, 0);
  o1 = __builtin_amdgcn_mfma_f32_32x32x16_bf16(va1[1], pb[1], o1, 0, 0, 0);
}

// ---------------- flash attention: swapped 32x32, paired chunks, split-K parity ----
__global__ __launch_bounds__(64) void attn_fwd(
    const __bf16* __restrict__ q_buf, const __bf16* __restrict__ k_buf,
    const __bf16* __restrict__ vT_buf, __bf16* __restrict__ o_part,
    float* __restrict__ ml_part) {
  const int lane = threadIdx.x;
  const int lq = lane & 31;
  const int hi = lane >> 5;
  const int bh = blockIdx.x;
  const int wv = blockIdx.y >> 1;
  const int hf = blockIdx.y & 1;
  const int h = bh & 15;
  const int cH = 63 - wv, cL = wv;
  const float slope2 = exp2f(-0.5f * (float)(h + 1)) * 1.44269504f;
  const __bf16* qp = q_buf + (size_t)bh * TSEQ * DH;
  const __bf16* kp = k_buf + (size_t)bh * TSEQ * DH;
  const __bf16* vp = vT_buf + (size_t)bh * DH * TSEQ;

  bf16x8 qfH[4], qfL[4];
#pragma unroll
  for (int m = 0; m < 4; ++m) {
    qfH[m] = *(const bf16x8*)&qp[(size_t)(cH * 32 + lq) * DH + m * 16 + hi * 8];
    qfL[m] = *(const bf16x8*)&qp[(size_t)(cL * 32 + lq) * DH + m * 16 + hi * 8];
  }
  float pk_[16];
#pragma unroll
  for (int r = 0; r < 16; ++r)
    pk_[r] = slope2 * (float)((r & 3) + 8 * (r >> 2) + 4 * hi);

  f32x16 oH0 = {}, oH1 = {}, oL0 = {}, oL1 = {};
  float mH = -__builtin_inff(), lH = 0.f, mL = -__builtin_inff(), lL = 0.f;

  bf16x8 kf[4];
#pragma unroll
  for (int m = 0; m < 4; ++m)
    kf[m] = *(const bf16x8*)&kp[(size_t)(hf * 32 + lq) * DH + m * 16 + hi * 8];

  for (int j = hf; j <= cH; j += 2) {
    const int kt = j * 32;
    bf16x8 va0[2], va1[2];
#pragma unroll
    for (int kh = 0; kh < 2; ++kh) {
      va0[kh] = *(const bf16x8*)&vp[(size_t)lq * TSEQ + kt + kh * 16 + hi * 8];
      va1[kh] = *(const bf16x8*)&vp[(size_t)(32 + lq) * TSEQ + kt + kh * 16 + hi * 8];
    }
    bf16x8 kn[4];
    const bool pre = (j + 2 <= cH);
    if (pre) {
#pragma unroll
      for (int m = 0; m < 4; ++m)
        kn[m] = *(const bf16x8*)&kp[(size_t)(kt + 64 + lq) * DH + m * 16 + hi * 8];
    }
    f32x16 sH = {};
#pragma unroll
    for (int m = 0; m < 4; ++m)
      sH = __builtin_amdgcn_mfma_f32_32x32x16_bf16(kf[m], qfH[m], sH, 0, 0, 0);
    const bool lact = (j <= cL);
    f32x16 sL = {};
    if (lact) {
#pragma unroll
      for (int m = 0; m < 4; ++m)
        sL = __builtin_amdgcn_mfma_f32_32x32x16_bf16(kf[m], qfL[m], sL, 0, 0, 0);
    }
    const float ktb = slope2 * (float)kt;
    softmax_pv(sH, j == cH, ktb, pk_, lq, hi, mH, lH, oH0, oH1, va0, va1);
    if (lact)
      softmax_pv(sL, j == cL, ktb, pk_, lq, hi, mL, lL, oL0, oL1, va0, va1);
    if (pre) {
#pragma unroll
      for (int m = 0; m < 4; ++m) kf[m] = kn[m];
    }
  }

#pragma unroll
  for (int g2 = 0; g2 < 2; ++g2) {
    const int c = g2 ? cL : cH;
    const f32x16& a0 = g2 ? oL0 : oH0;
    const f32x16& a1 = g2 ? oL1 : oH1;
    const float mv = g2 ? mL : mH;
    const float lv = g2 ? lL : lH;
    const size_t slot = (size_t)hf * 2048 + (size_t)bh * 64 + c;
    __bf16* op = o_part + slot * 2048 + (size_t)lq * 64;
#pragma unroll
    for (int g = 0; g < 4; ++g) {
      bf16x4 v0, v1;
#pragma unroll
      for (int e = 0; e < 4; ++e) {
        v0[e] = (__bf16)a0[4 * g + e];
        v1[e] = (__bf16)a1[4 * g + e];
      }
      *(bf16x4*)&op[8 * g + 4 * hi] = v0;
      *(bf16x4*)&op[32 + 8 * g + 4 * hi] = v1;
    }
    if (hi == 0) {
      ml_part[slot * 64 + lq] = mv;
      ml_part[slot * 64 + 32 + lq] = lv;
    }
  }
}

// ---------------- combine the two parity halves ----------------
__global__ __launch_bounds__(256) void attn_combine(
    const __bf16* __restrict__ o_part, const float* __restrict__ ml,
    __bf16* __restrict__ y_buf) {
  const int tid = threadIdx.x;
  const int t8 = tid & 7, rloc = tid >> 3;
  const int row = blockIdx.x * 32 + rloc;
  const int slot = row >> 5, lq = row & 31;
  const int bh = slot >> 6, cc = slot & 63;
  const int b = bh >> 4, h = bh & 15;
  float m0 = ml[(size_t)slot * 64 + lq], l0 = ml[(size_t)slot * 64 + 32 + lq];
  float m1 = ml[(size_t)(2048 + slot) * 64 + lq], l1 = ml[(size_t)(2048 + slot) * 64 + 32 + lq];
  float mm = fmaxf(m0, m1);
  float e0 = fexp2(m0 - mm), e1 = fexp2(m1 - mm);
  float inv = 1.0f / (l0 * e0 + l1 * e1);
  float s0 = e0 * inv, s1 = e1 * inv;
  bf16x8 a = *(const bf16x8*)(o_part + (size_t)slot * 2048 + (size_t)lq * 64 + t8 * 8);
  bf16x8 c2 = *(const bf16x8*)(o_part + (size_t)(2048 + slot) * 2048 + (size_t)lq * 64 + t8 * 8);
  bf16x8 r;
#pragma unroll
  for (int e = 0; e < 8; ++e)
    r[e] = (__bf16)((float)a[e] * s0 + (float)c2[e] * s1);
  const int t = cc * 32 + lq;
  *(bf16x8*)&y_buf[((size_t)b * TSEQ + t) * CDIM + h * DH + t8 * 8] = r;
}

extern "C" void kernel_launch(void* const* d_in, const int* in_sizes, int n_in,
                              void* d_out, int out_size, void* d_ws, size_t ws_size,
                              hipStream_t stream) {
  const float* x      = (const float*)d_in[0];
  const float* W_attn = (const float*)d_in[1];
  const float* b_attn = (const float*)d_in[2];
  const float* W_proj = (const float*)d_in[3];
  const float* b_proj = (const float*)d_in[4];
  float* out = (float*)d_out;
  char* ws = (char*)d_ws;
  const size_t MB = (size_t)1 << 20;
  __bf16* xb  = (__bf16*)(ws + 0 * MB);
  __bf16* wab = (__bf16*)(ws + 8 * MB);
  __bf16* wpb = (__bf16*)(ws + 14 * MB);
  __bf16* qbf = (__bf16*)(ws + 16 * MB);
  __bf16* kbf = (__bf16*)(ws + 24 * MB);
  __bf16* vtb = (__bf16*)(ws + 32 * MB);
  __bf16* yb  = (__bf16*)(ws + 40 * MB);
  float*  mlp = (float*)(ws + 0 * MB);
  __bf16* opart = (__bf16*)d_out;

  cvt_bf16<<<2048, 256, 0, stream>>>(x, xb, 524288);
  cvt_bf16<<<1536, 256, 0, stream>>>(W_attn, wab, 393216);
  cvt_bf16<<<512, 256, 0, stream>>>(W_proj, wpb, 131072);

  gemm_bt<1><<<dim3(24, 32), 256, 0, stream>>>(xb, wab, b_attn, nullptr,
                                               qbf, kbf, vtb, 4096, 3072, 1024);
  attn_fwd<<<dim3(32, 64), 64, 0, stream>>>(qbf, kbf, vtb, opart, mlp);
  attn_combine<<<2048, 256, 0, stream>>>(opart, mlp, yb);
  gemm_bt<0><<<dim3(8, 32), 256, 0, stream>>>(yb, wpb, b_proj, out,
                                              nullptr, nullptr, nullptr, 4096, 1024, 1024);
}

// Round 12
// 138.768 us; speedup vs baseline: 1.5174x; 1.0384x over previous
//
#include <hip/hip_runtime.h>

typedef __bf16 bf16x8 __attribute__((ext_vector_type(8)));
typedef __bf16 bf16x4 __attribute__((ext_vector_type(4)));
typedef float  f32x4  __attribute__((ext_vector_type(4)));
typedef float  f32x16 __attribute__((ext_vector_type(16)));

#define TSEQ 2048
#define CDIM 1024
#define NHEAD 16
#define DH 64
#define SCALE2 0.1803368801111137f  // 0.125 * log2(e)

__device__ __forceinline__ void gl_lds16(const void* g, void* l) {
  __builtin_amdgcn_global_load_lds(
      (const __attribute__((address_space(1))) unsigned int*)g,
      (__attribute__((address_space(3))) unsigned int*)l, 16, 0, 0);
}

__device__ __forceinline__ float fexp2(float x) { return __builtin_amdgcn_exp2f(x); }

__device__ __forceinline__ unsigned cvtpk(float a, float b) {
  unsigned r;
  asm("v_cvt_pk_bf16_f32 %0, %1, %2" : "=v"(r) : "v"(a), "v"(b));
  return r;
}
__device__ __forceinline__ void permswap(unsigned& x, unsigned& y) {
  asm("v_permlane32_swap_b32 %0, %1" : "+v"(x), "+v"(y));
}

__device__ __forceinline__ float tsum16(const f32x16& s) {
  float a0 = s[0] + s[1], a1 = s[2] + s[3], a2 = s[4] + s[5], a3 = s[6] + s[7];
  float a4 = s[8] + s[9], a5 = s[10] + s[11], a6 = s[12] + s[13], a7 = s[14] + s[15];
  float b0 = a0 + a1, b1 = a2 + a3, b2 = a4 + a5, b3 = a6 + a7;
  return (b0 + b1) + (b2 + b3);
}

// ---------------- fp32 -> bf16 conversion (vectorized) ----------------
__global__ __launch_bounds__(256) void cvt_bf16(const float* __restrict__ in,
                                                __bf16* __restrict__ out, int n8) {
  int i = blockIdx.x * 256 + threadIdx.x;
  if (i >= n8) return;
  const float4* p = (const float4*)(in + (size_t)i * 8);
  float4 a = p[0], b = p[1];
  bf16x8 r;
  r[0] = (__bf16)a.x; r[1] = (__bf16)a.y; r[2] = (__bf16)a.z; r[3] = (__bf16)a.w;
  r[4] = (__bf16)b.x; r[5] = (__bf16)b.y; r[6] = (__bf16)b.z; r[7] = (__bf16)b.w;
  *(bf16x8*)(out + (size_t)i * 8) = r;
}

// ---------------- bf16 GEMM (m97-style + T2 swizzle): out = A*Bw^T + bias --------
// Pre-swizzled global source (slot s^(row&7)) + linear LDS dest + swizzled ds_read.
// EPI=1 scatters qkv; q is PRE-SCALED by 0.125*log2e.
template <int EPI>
__global__ __launch_bounds__(256) void gemm_bt(
    const __bf16* __restrict__ A, const __bf16* __restrict__ Bw,
    const float* __restrict__ bias, float* __restrict__ outf,
    __bf16* __restrict__ q_buf, __bf16* __restrict__ k_buf,
    __bf16* __restrict__ vT_buf, int M, int N, int K) {
  __shared__ alignas(16) __bf16 lda[128 * 64];
  __shared__ alignas(16) __bf16 ldb[128 * 64];
  const int tid = threadIdx.x;
  const int lane = tid & 63, wid = tid >> 6;
  const int wm = wid >> 1, wn = wid & 1;
  const int row0 = blockIdx.y * 128, col0 = blockIdx.x * 128;
  f32x4 acc[4][4] = {};

  const int srow = lane >> 3;
  const int scb = ((lane & 7) ^ (lane >> 3)) * 16;

  for (int k0 = 0; k0 < K; k0 += 64) {
#pragma unroll
    for (int j = 0; j < 4; ++j) {
      int blk = j * 4 + wid;
      int r = blk * 8 + srow;
      char* la = (char*)lda + blk * 1024;
      char* lb = (char*)ldb + blk * 1024;
      gl_lds16((const char*)(A + (size_t)(row0 + r) * K + k0) + scb, la);
      gl_lds16((const char*)(Bw + (size_t)(col0 + r) * K + k0) + scb, lb);
    }
    __syncthreads();
#pragma unroll
    for (int kk = 0; kk < 2; ++kk) {
      const int sl = (((kk << 2) | (lane >> 4)) ^ (lane & 7)) * 16;
      bf16x8 af[4], bfr[4];
#pragma unroll
      for (int m = 0; m < 4; ++m)
        af[m] = *(const bf16x8*)((const char*)lda +
                                 (wm * 64 + m * 16 + (lane & 15)) * 128 + sl);
#pragma unroll
      for (int n = 0; n < 4; ++n)
        bfr[n] = *(const bf16x8*)((const char*)ldb +
                                  (wn * 64 + n * 16 + (lane & 15)) * 128 + sl);
#pragma unroll
      for (int m = 0; m < 4; ++m)
#pragma unroll
        for (int n = 0; n < 4; ++n)
          acc[m][n] = __builtin_amdgcn_mfma_f32_16x16x32_bf16(af[m], bfr[n], acc[m][n], 0, 0, 0);
    }
    __syncthreads();
  }
#pragma unroll
  for (int m = 0; m < 4; ++m) {
#pragma unroll
    for (int n = 0; n < 4; ++n) {
#pragma unroll
      for (int i = 0; i < 4; ++i) {
        int r = row0 + wm * 64 + m * 16 + (lane >> 4) * 4 + i;
        int c = col0 + wn * 64 + n * 16 + (lane & 15);
        float v = acc[m][n][i] + bias[c];
        if (EPI == 0) {
          outf[(size_t)r * N + c] = v;
        } else {
          int bb = r >> 11, t = r & 2047;
          int sec = c >> 10, cc = c & 1023;
          int hh = cc >> 6, d = cc & 63;
          size_t bh = (size_t)bb * NHEAD + hh;
          if (sec == 0)      q_buf[(bh * TSEQ + (size_t)t) * DH + d] = (__bf16)(v * SCALE2);
          else if (sec == 1) k_buf[(bh * TSEQ + (size_t)t) * DH + d] = (__bf16)v;
          else               vT_buf[(bh * DH + (size_t)d) * TSEQ + t] = (__bf16)v;
        }
      }
    }
  }
}

// ---------------- attention: fixed-reference softmax (no max tracking) ----------
// P = exp2(s) where s already contains qk + slope2*(kc - q0). Per-lane residual row
// factor 2^(slope2*lq) cancels in o/l (o,l same lane). Magnitudes bounded: s <= ~45
// on-diagonal -> P <= 2^45, l <= 2^56, all fp32/bf16-safe.
__device__ __forceinline__ void softmax_pv(
    f32x16& s, bool domask, int lq, int hi,
    float& l_r, f32x16& o0, f32x16& o1,
    const bf16x8* va0, const bf16x8* va1) {
#pragma unroll
  for (int r = 0; r < 16; ++r) s[r] = fexp2(s[r]);
  if (domask) {
#pragma unroll
    for (int r = 0; r < 16; ++r) {
      int kof = (r & 3) + 8 * (r >> 2) + 4 * hi;
      if (kof > lq) s[r] = 0.f;
    }
  }
  float rs = tsum16(s);
  rs += __shfl_xor(rs, 32, 64);
  l_r += rs;
  bf16x8 pb[2];
#pragma unroll
  for (int kh = 0; kh < 2; ++kh) {
    const int bq = kh * 8;
    unsigned w0 = cvtpk(s[bq + 0], s[bq + 1]);
    unsigned w1 = cvtpk(s[bq + 2], s[bq + 3]);
    unsigned w2 = cvtpk(s[bq + 4], s[bq + 5]);
    unsigned w3 = cvtpk(s[bq + 6], s[bq + 7]);
    permswap(w0, w2);
    permswap(w1, w3);
    union { unsigned u[4]; bf16x8 v; } pbu;
    pbu.u[0] = w0; pbu.u[1] = w1; pbu.u[2] = w2; pbu.u[3] = w3;
    pb[kh] = pbu.v;
  }
  o0 = __builtin_amdgcn_mfma_f32_32x32x16_bf16(va0[0], pb[0], o0, 0, 0, 0);
  o0 = __builtin_amdgcn_mfma_f32_32x32x16_bf16(va0[1], pb[1], o0, 0, 0, 0);
  o1 = __builtin_amdgcn_mfma_f32_32x32x16_bf16(va1[0], pb[0], o1, 0, 0, 0);
  o1 = __builtin_amdgcn_mfma_f32_32x32x16_bf16(va1[1], pb[1], o1, 0, 0, 0);
}

// ---------------- flash attention: swapped 32x32, paired chunks, split-K parity ----
// ALiBi bias (pk_ + slope2*(kt-q0)) folded into the MFMA C-initializer: zero extra
// VALU on the S path beyond 16 binit adds per chunk-tile.
__global__ __launch_bounds__(64) void attn_fwd(
    const __bf16* __restrict__ q_buf, const __bf16* __restrict__ k_buf,
    const __bf16* __restrict__ vT_buf, __bf16* __restrict__ o_part,
    float* __restrict__ l_part) {
  const int lane = threadIdx.x;
  const int lq = lane & 31;
  const int hi = lane >> 5;
  const int bh = blockIdx.x;
  const int wv = blockIdx.y >> 1;
  const int hf = blockIdx.y & 1;
  const int h = bh & 15;
  const int cH = 63 - wv, cL = wv;
  const float slope2 = exp2f(-0.5f * (float)(h + 1)) * 1.44269504f;
  const __bf16* qp = q_buf + (size_t)bh * TSEQ * DH;
  const __bf16* kp = k_buf + (size_t)bh * TSEQ * DH;
  const __bf16* vp = vT_buf + (size_t)bh * DH * TSEQ;

  bf16x8 qfH[4], qfL[4];
#pragma unroll
  for (int m = 0; m < 4; ++m) {
    qfH[m] = *(const bf16x8*)&qp[(size_t)(cH * 32 + lq) * DH + m * 16 + hi * 8];
    qfL[m] = *(const bf16x8*)&qp[(size_t)(cL * 32 + lq) * DH + m * 16 + hi * 8];
  }
  float pk_[16];
#pragma unroll
  for (int r = 0; r < 16; ++r)
    pk_[r] = slope2 * (float)((r & 3) + 8 * (r >> 2) + 4 * hi);

  f32x16 oH0 = {}, oH1 = {}, oL0 = {}, oL1 = {};
  float lH = 0.f, lL = 0.f;

  bf16x8 kf[4];
#pragma unroll
  for (int m = 0; m < 4; ++m)
    kf[m] = *(const bf16x8*)&kp[(size_t)(hf * 32 + lq) * DH + m * 16 + hi * 8];

  for (int j = hf; j <= cH; j += 2) {
    const int kt = j * 32;
    bf16x8 va0[2], va1[2];
#pragma unroll
    for (int kh = 0; kh < 2; ++kh) {
      va0[kh] = *(const bf16x8*)&vp[(size_t)lq * TSEQ + kt + kh * 16 + hi * 8];
      va1[kh] = *(const bf16x8*)&vp[(size_t)(32 + lq) * TSEQ + kt + kh * 16 + hi * 8];
    }
    bf16x8 kn[4];
    const bool pre = (j + 2 <= cH);
    if (pre) {
#pragma unroll
      for (int m = 0; m < 4; ++m)
        kn[m] = *(const bf16x8*)&kp[(size_t)(kt + 64 + lq) * DH + m * 16 + hi * 8];
    }
    // bias as MFMA C-init: s starts at pk_ + slope2*(kt - q0)
    const float bH = slope2 * (float)(kt - cH * 32);
    f32x16 sH;
#pragma unroll
    for (int r = 0; r < 16; ++r) sH[r] = pk_[r] + bH;
    sH = __builtin_amdgcn_mfma_f32_32x32x16_bf16(kf[0], qfH[0], sH, 0, 0, 0);
#pragma unroll
    for (int m = 1; m < 4; ++m)
      sH = __builtin_amdgcn_mfma_f32_32x32x16_bf16(kf[m], qfH[m], sH, 0, 0, 0);
    const bool lact = (j <= cL);
    f32x16 sL;
    if (lact) {
      const float bL = slope2 * (float)(kt - cL * 32);
#pragma unroll
      for (int r = 0; r < 16; ++r) sL[r] = pk_[r] + bL;
      sL = __builtin_amdgcn_mfma_f32_32x32x16_bf16(kf[0], qfL[0], sL, 0, 0, 0);
#pragma unroll
      for (int m = 1; m < 4; ++m)
        sL = __builtin_amdgcn_mfma_f32_32x32x16_bf16(kf[m], qfL[m], sL, 0, 0, 0);
    }
    softmax_pv(sH, j == cH, lq, hi, lH, oH0, oH1, va0, va1);
    if (lact)
      softmax_pv(sL, j == cL, lq, hi, lL, oL0, oL1, va0, va1);
    if (pre) {
#pragma unroll
      for (int m = 0; m < 4; ++m) kf[m] = kn[m];
    }
  }

#pragma unroll
  for (int g2 = 0; g2 < 2; ++g2) {
    const int c = g2 ? cL : cH;
    const f32x16& a0 = g2 ? oL0 : oH0;
    const f32x16& a1 = g2 ? oL1 : oH1;
    const float lv = g2 ? lL : lH;
    const size_t slot = (size_t)hf * 2048 + (size_t)bh * 64 + c;
    __bf16* op = o_part + slot * 2048 + (size_t)lq * 64;
#pragma unroll
    for (int g = 0; g < 4; ++g) {
      bf16x4 v0, v1;
#pragma unroll
      for (int e = 0; e < 4; ++e) {
        v0[e] = (__bf16)a0[4 * g + e];
        v1[e] = (__bf16)a1[4 * g + e];
      }
      *(bf16x4*)&op[8 * g + 4 * hi] = v0;
      *(bf16x4*)&op[32 + 8 * g + 4 * hi] = v1;
    }
    if (hi == 0) l_part[slot * 32 + lq] = lv;
  }
}

// ---------------- combine the two parity halves (shared fixed reference) --------
__global__ __launch_bounds__(256) void attn_combine(
    const __bf16* __restrict__ o_part, const float* __restrict__ lp,
    __bf16* __restrict__ y_buf) {
  const int tid = threadIdx.x;
  const int t8 = tid & 7, rloc = tid >> 3;
  const int row = blockIdx.x * 32 + rloc;
  const int slot = row >> 5, lq = row & 31;
  const int bh = slot >> 6, cc = slot & 63;
  const int b = bh >> 4, h = bh & 15;
  float l0 = lp[(size_t)slot * 32 + lq];
  float l1 = lp[(size_t)(2048 + slot) * 32 + lq];
  float inv = 1.0f / (l0 + l1);
  bf16x8 a = *(const bf16x8*)(o_part + (size_t)slot * 2048 + (size_t)lq * 64 + t8 * 8);
  bf16x8 c2 = *(const bf16x8*)(o_part + (size_t)(2048 + slot) * 2048 + (size_t)lq * 64 + t8 * 8);
  bf16x8 r;
#pragma unroll
  for (int e = 0; e < 8; ++e)
    r[e] = (__bf16)(((float)a[e] + (float)c2[e]) * inv);
  const int t = cc * 32 + lq;
  *(bf16x8*)&y_buf[((size_t)b * TSEQ + t) * CDIM + h * DH + t8 * 8] = r;
}

extern "C" void kernel_launch(void* const* d_in, const int* in_sizes, int n_in,
                              void* d_out, int out_size, void* d_ws, size_t ws_size,
                              hipStream_t stream) {
  const float* x      = (const float*)d_in[0];
  const float* W_attn = (const float*)d_in[1];
  const float* b_attn = (const float*)d_in[2];
  const float* W_proj = (const float*)d_in[3];
  const float* b_proj = (const float*)d_in[4];
  float* out = (float*)d_out;
  char* ws = (char*)d_ws;
  const size_t MB = (size_t)1 << 20;
  __bf16* xb  = (__bf16*)(ws + 0 * MB);
  __bf16* wab = (__bf16*)(ws + 8 * MB);
  __bf16* wpb = (__bf16*)(ws + 14 * MB);
  __bf16* qbf = (__bf16*)(ws + 16 * MB);
  __bf16* kbf = (__bf16*)(ws + 24 * MB);
  __bf16* vtb = (__bf16*)(ws + 32 * MB);
  __bf16* yb  = (__bf16*)(ws + 40 * MB);
  float*  lpt = (float*)(ws + 0 * MB);    // 512 KB over dead xb
  __bf16* opart = (__bf16*)d_out;         // 16.78 MB scratch; proj overwrites after

  cvt_bf16<<<2048, 256, 0, stream>>>(x, xb, 524288);
  cvt_bf16<<<1536, 256, 0, stream>>>(W_attn, wab, 393216);
  cvt_bf16<<<512, 256, 0, stream>>>(W_proj, wpb, 131072);

  gemm_bt<1><<<dim3(24, 32), 256, 0, stream>>>(xb, wab, b_attn, nullptr,
                                               qbf, kbf, vtb, 4096, 3072, 1024);
  attn_fwd<<<dim3(32, 64), 64, 0, stream>>>(qbf, kbf, vtb, opart, lpt);
  attn_combine<<<2048, 256, 0, stream>>>(opart, lpt, yb);
  gemm_bt<0><<<dim3(8, 32), 256, 0, stream>>>(yb, wpb, b_proj, out,
                                              nullptr, nullptr, nullptr, 4096, 1024, 1024);
}

// Round 13
// 138.016 us; speedup vs baseline: 1.5257x; 1.0054x over previous
//
#include <hip/hip_runtime.h>

typedef __bf16 bf16x8 __attribute__((ext_vector_type(8)));
typedef __bf16 bf16x4 __attribute__((ext_vector_type(4)));
typedef float  f32x4  __attribute__((ext_vector_type(4)));
typedef float  f32x16 __attribute__((ext_vector_type(16)));

#define TSEQ 2048
#define CDIM 1024
#define NHEAD 16
#define DH 64
#define SCALE2 0.1803368801111137f  // 0.125 * log2(e)

__device__ __forceinline__ void gl_lds16(const void* g, void* l) {
  __builtin_amdgcn_global_load_lds(
      (const __attribute__((address_space(1))) unsigned int*)g,
      (__attribute__((address_space(3))) unsigned int*)l, 16, 0, 0);
}

__device__ __forceinline__ float fexp2(float x) { return __builtin_amdgcn_exp2f(x); }

__device__ __forceinline__ unsigned cvtpk(float a, float b) {
  unsigned r;
  asm("v_cvt_pk_bf16_f32 %0, %1, %2" : "=v"(r) : "v"(a), "v"(b));
  return r;
}
__device__ __forceinline__ void permswap(unsigned& x, unsigned& y) {
  asm("v_permlane32_swap_b32 %0, %1" : "+v"(x), "+v"(y));
}

__device__ __forceinline__ float tsum16(const f32x16& s) {
  float a0 = s[0] + s[1], a1 = s[2] + s[3], a2 = s[4] + s[5], a3 = s[6] + s[7];
  float a4 = s[8] + s[9], a5 = s[10] + s[11], a6 = s[12] + s[13], a7 = s[14] + s[15];
  float b0 = a0 + a1, b1 = a2 + a3, b2 = a4 + a5, b3 = a6 + a7;
  return (b0 + b1) + (b2 + b3);
}

// ---------------- fp32 -> bf16 conversion (merged, 1 launch) ----------------
__global__ __launch_bounds__(256) void cvt_bf16_all(
    const float* __restrict__ x, const float* __restrict__ wa,
    const float* __restrict__ wp, __bf16* __restrict__ xb,
    __bf16* __restrict__ wab, __bf16* __restrict__ wpb) {
  int i = blockIdx.x * 256 + threadIdx.x;  // 0..1048575 (x8 elems)
  const float* in;
  __bf16* out;
  int off;
  if (i < 524288)      { in = x;  out = xb;  off = i; }
  else if (i < 917504) { in = wa; out = wab; off = i - 524288; }
  else                 { in = wp; out = wpb; off = i - 917504; }
  const float4* p = (const float4*)(in + (size_t)off * 8);
  float4 a = p[0], b = p[1];
  bf16x8 r;
  r[0] = (__bf16)a.x; r[1] = (__bf16)a.y; r[2] = (__bf16)a.z; r[3] = (__bf16)a.w;
  r[4] = (__bf16)b.x; r[5] = (__bf16)b.y; r[6] = (__bf16)b.z; r[7] = (__bf16)b.w;
  *(bf16x8*)(out + (size_t)off * 8) = r;
}

// ---------------- bf16 GEMM (m97-style + T2 swizzle): out = A*Bw^T + bias --------
template <int EPI>
__global__ __launch_bounds__(256) void gemm_bt(
    const __bf16* __restrict__ A, const __bf16* __restrict__ Bw,
    const float* __restrict__ bias, float* __restrict__ outf,
    __bf16* __restrict__ q_buf, __bf16* __restrict__ k_buf,
    __bf16* __restrict__ vT_buf, int M, int N, int K) {
  __shared__ alignas(16) __bf16 lda[128 * 64];
  __shared__ alignas(16) __bf16 ldb[128 * 64];
  const int tid = threadIdx.x;
  const int lane = tid & 63, wid = tid >> 6;
  const int wm = wid >> 1, wn = wid & 1;
  const int row0 = blockIdx.y * 128, col0 = blockIdx.x * 128;
  f32x4 acc[4][4] = {};

  const int srow = lane >> 3;
  const int scb = ((lane & 7) ^ (lane >> 3)) * 16;

  for (int k0 = 0; k0 < K; k0 += 64) {
#pragma unroll
    for (int j = 0; j < 4; ++j) {
      int blk = j * 4 + wid;
      int r = blk * 8 + srow;
      char* la = (char*)lda + blk * 1024;
      char* lb = (char*)ldb + blk * 1024;
      gl_lds16((const char*)(A + (size_t)(row0 + r) * K + k0) + scb, la);
      gl_lds16((const char*)(Bw + (size_t)(col0 + r) * K + k0) + scb, lb);
    }
    __syncthreads();
#pragma unroll
    for (int kk = 0; kk < 2; ++kk) {
      const int sl = (((kk << 2) | (lane >> 4)) ^ (lane & 7)) * 16;
      bf16x8 af[4], bfr[4];
#pragma unroll
      for (int m = 0; m < 4; ++m)
        af[m] = *(const bf16x8*)((const char*)lda +
                                 (wm * 64 + m * 16 + (lane & 15)) * 128 + sl);
#pragma unroll
      for (int n = 0; n < 4; ++n)
        bfr[n] = *(const bf16x8*)((const char*)ldb +
                                  (wn * 64 + n * 16 + (lane & 15)) * 128 + sl);
#pragma unroll
      for (int m = 0; m < 4; ++m)
#pragma unroll
        for (int n = 0; n < 4; ++n)
          acc[m][n] = __builtin_amdgcn_mfma_f32_16x16x32_bf16(af[m], bfr[n], acc[m][n], 0, 0, 0);
    }
    __syncthreads();
  }
#pragma unroll
  for (int m = 0; m < 4; ++m) {
#pragma unroll
    for (int n = 0; n < 4; ++n) {
#pragma unroll
      for (int i = 0; i < 4; ++i) {
        int r = row0 + wm * 64 + m * 16 + (lane >> 4) * 4 + i;
        int c = col0 + wn * 64 + n * 16 + (lane & 15);
        float v = acc[m][n][i] + bias[c];
        if (EPI == 0) {
          outf[(size_t)r * N + c] = v;
        } else {
          int bb = r >> 11, t = r & 2047;
          int sec = c >> 10, cc = c & 1023;
          int hh = cc >> 6, d = cc & 63;
          size_t bh = (size_t)bb * NHEAD + hh;
          if (sec == 0)      q_buf[(bh * TSEQ + (size_t)t) * DH + d] = (__bf16)(v * SCALE2);
          else if (sec == 1) k_buf[(bh * TSEQ + (size_t)t) * DH + d] = (__bf16)v;
          else               vT_buf[(bh * DH + (size_t)d) * TSEQ + t] = (__bf16)v;
        }
      }
    }
  }
}

// ---------------- attention: fixed-ref softmax; sA+sB fused into exp pass --------
__device__ __forceinline__ void softmax_pv(
    const f32x16& sa, const f32x16& sb, bool domask, int lq, int hi,
    float& l_r, f32x16& o0, f32x16& o1,
    const bf16x8* va0, const bf16x8* va1) {
  f32x16 s;
#pragma unroll
  for (int r = 0; r < 16; ++r) s[r] = fexp2(sa[r] + sb[r]);
  if (domask) {
#pragma unroll
    for (int r = 0; r < 16; ++r) {
      int kof = (r & 3) + 8 * (r >> 2) + 4 * hi;
      if (kof > lq) s[r] = 0.f;
    }
  }
  l_r += tsum16(s);  // per-hi-half partial; cross-half shfl deferred to kernel end
  bf16x8 pb[2];
#pragma unroll
  for (int kh = 0; kh < 2; ++kh) {
    const int bq = kh * 8;
    unsigned w0 = cvtpk(s[bq + 0], s[bq + 1]);
    unsigned w1 = cvtpk(s[bq + 2], s[bq + 3]);
    unsigned w2 = cvtpk(s[bq + 4], s[bq + 5]);
    unsigned w3 = cvtpk(s[bq + 6], s[bq + 7]);
    permswap(w0, w2);
    permswap(w1, w3);
    union { unsigned u[4]; bf16x8 v; } pbu;
    pbu.u[0] = w0; pbu.u[1] = w1; pbu.u[2] = w2; pbu.u[3] = w3;
    pb[kh] = pbu.v;
  }
  __builtin_amdgcn_s_setprio(1);
  o0 = __builtin_amdgcn_mfma_f32_32x32x16_bf16(va0[0], pb[0], o0, 0, 0, 0);
  o0 = __builtin_amdgcn_mfma_f32_32x32x16_bf16(va0[1], pb[1], o0, 0, 0, 0);
  o1 = __builtin_amdgcn_mfma_f32_32x32x16_bf16(va1[0], pb[0], o1, 0, 0, 0);
  o1 = __builtin_amdgcn_mfma_f32_32x32x16_bf16(va1[1], pb[1], o1, 0, 0, 0);
  __builtin_amdgcn_s_setprio(0);
}

// ---------------- flash attention: swapped 32x32, paired chunks, split-K parity ----
__global__ __launch_bounds__(64) void attn_fwd(
    const __bf16* __restrict__ q_buf, const __bf16* __restrict__ k_buf,
    const __bf16* __restrict__ vT_buf, __bf16* __restrict__ o_part,
    float* __restrict__ l_part) {
  const int lane = threadIdx.x;
  const int lq = lane & 31;
  const int hi = lane >> 5;
  const int bh = blockIdx.x;
  const int wv = blockIdx.y >> 1;
  const int hf = blockIdx.y & 1;
  const int h = bh & 15;
  const int cH = 63 - wv, cL = wv;
  const float slope2 = exp2f(-0.5f * (float)(h + 1)) * 1.44269504f;
  const __bf16* qp = q_buf + (size_t)bh * TSEQ * DH;
  const __bf16* kp = k_buf + (size_t)bh * TSEQ * DH;
  const __bf16* vp = vT_buf + (size_t)bh * DH * TSEQ;

  bf16x8 qfH[4], qfL[4];
#pragma unroll
  for (int m = 0; m < 4; ++m) {
    qfH[m] = *(const bf16x8*)&qp[(size_t)(cH * 32 + lq) * DH + m * 16 + hi * 8];
    qfL[m] = *(const bf16x8*)&qp[(size_t)(cL * 32 + lq) * DH + m * 16 + hi * 8];
  }
  float pk_[16];
#pragma unroll
  for (int r = 0; r < 16; ++r)
    pk_[r] = slope2 * (float)((r & 3) + 8 * (r >> 2) + 4 * hi);

  f32x16 oH0 = {}, oH1 = {}, oL0 = {}, oL1 = {};
  float lH = 0.f, lL = 0.f;

  bf16x8 kf[4];
#pragma unroll
  for (int m = 0; m < 4; ++m)
    kf[m] = *(const bf16x8*)&kp[(size_t)(hf * 32 + lq) * DH + m * 16 + hi * 8];

  for (int j = hf; j <= cH; j += 2) {
    const int kt = j * 32;
    bf16x8 va0[2], va1[2];
#pragma unroll
    for (int kh = 0; kh < 2; ++kh) {
      va0[kh] = *(const bf16x8*)&vp[(size_t)lq * TSEQ + kt + kh * 16 + hi * 8];
      va1[kh] = *(const bf16x8*)&vp[(size_t)(32 + lq) * TSEQ + kt + kh * 16 + hi * 8];
    }
    bf16x8 kn[4];
    const bool pre = (j + 2 <= cH);
    if (pre) {
#pragma unroll
      for (int m = 0; m < 4; ++m)
        kn[m] = *(const bf16x8*)&kp[(size_t)(kt + 64 + lq) * DH + m * 16 + hi * 8];
    }
    // S as two independent 2-MFMA chains (bias in chain-A's C-init)
    const float bH = slope2 * (float)(kt - cH * 32);
    f32x16 sHa, sHb = {};
#pragma unroll
    for (int r = 0; r < 16; ++r) sHa[r] = pk_[r] + bH;
    __builtin_amdgcn_s_setprio(1);
    sHa = __builtin_amdgcn_mfma_f32_32x32x16_bf16(kf[0], qfH[0], sHa, 0, 0, 0);
    sHb = __builtin_amdgcn_mfma_f32_32x32x16_bf16(kf[2], qfH[2], sHb, 0, 0, 0);
    sHa = __builtin_amdgcn_mfma_f32_32x32x16_bf16(kf[1], qfH[1], sHa, 0, 0, 0);
    sHb = __builtin_amdgcn_mfma_f32_32x32x16_bf16(kf[3], qfH[3], sHb, 0, 0, 0);
    __builtin_amdgcn_s_setprio(0);
    const bool lact = (j <= cL);
    f32x16 sLa, sLb = {};
    if (lact) {
      const float bL = slope2 * (float)(kt - cL * 32);
#pragma unroll
      for (int r = 0; r < 16; ++r) sLa[r] = pk_[r] + bL;
      __builtin_amdgcn_s_setprio(1);
      sLa = __builtin_amdgcn_mfma_f32_32x32x16_bf16(kf[0], qfL[0], sLa, 0, 0, 0);
      sLb = __builtin_amdgcn_mfma_f32_32x32x16_bf16(kf[2], qfL[2], sLb, 0, 0, 0);
      sLa = __builtin_amdgcn_mfma_f32_32x32x16_bf16(kf[1], qfL[1], sLa, 0, 0, 0);
      sLb = __builtin_amdgcn_mfma_f32_32x32x16_bf16(kf[3], qfL[3], sLb, 0, 0, 0);
      __builtin_amdgcn_s_setprio(0);
    }
    softmax_pv(sHa, sHb, j == cH, lq, hi, lH, oH0, oH1, va0, va1);
    if (lact)
      softmax_pv(sLa, sLb, j == cL, lq, hi, lL, oL0, oL1, va0, va1);
    if (pre) {
#pragma unroll
      for (int m = 0; m < 4; ++m) kf[m] = kn[m];
    }
  }
  // deferred cross-half l reduction (once, not per-iter)
  lH += __shfl_xor(lH, 32, 64);
  lL += __shfl_xor(lL, 32, 64);

#pragma unroll
  for (int g2 = 0; g2 < 2; ++g2) {
    const int c = g2 ? cL : cH;
    const f32x16& a0 = g2 ? oL0 : oH0;
    const f32x16& a1 = g2 ? oL1 : oH1;
    const float lv = g2 ? lL : lH;
    const size_t slot = (size_t)hf * 2048 + (size_t)bh * 64 + c;
    __bf16* op = o_part + slot * 2048 + (size_t)lq * 64;
#pragma unroll
    for (int g = 0; g < 4; ++g) {
      bf16x4 v0, v1;
#pragma unroll
      for (int e = 0; e < 4; ++e) {
        v0[e] = (__bf16)a0[4 * g + e];
        v1[e] = (__bf16)a1[4 * g + e];
      }
      *(bf16x4*)&op[8 * g + 4 * hi] = v0;
      *(bf16x4*)&op[32 + 8 * g + 4 * hi] = v1;
    }
    if (hi == 0) l_part[slot * 32 + lq] = lv;
  }
}

// ---------------- combine the two parity halves (shared fixed reference) --------
__global__ __launch_bounds__(256) void attn_combine(
    const __bf16* __restrict__ o_part, const float* __restrict__ lp,
    __bf16* __restrict__ y_buf) {
  const int tid = threadIdx.x;
  const int t8 = tid & 7, rloc = tid >> 3;
  const int row = blockIdx.x * 32 + rloc;
  const int slot = row >> 5, lq = row & 31;
  const int bh = slot >> 6, cc = slot & 63;
  const int b = bh >> 4, h = bh & 15;
  float l0 = lp[(size_t)slot * 32 + lq];
  float l1 = lp[(size_t)(2048 + slot) * 32 + lq];
  float inv = 1.0f / (l0 + l1);
  bf16x8 a = *(const bf16x8*)(o_part + (size_t)slot * 2048 + (size_t)lq * 64 + t8 * 8);
  bf16x8 c2 = *(const bf16x8*)(o_part + (size_t)(2048 + slot) * 2048 + (size_t)lq * 64 + t8 * 8);
  bf16x8 r;
#pragma unroll
  for (int e = 0; e < 8; ++e)
    r[e] = (__bf16)(((float)a[e] + (float)c2[e]) * inv);
  const int t = cc * 32 + lq;
  *(bf16x8*)&y_buf[((size_t)b * TSEQ + t) * CDIM + h * DH + t8 * 8] = r;
}

extern "C" void kernel_launch(void* const* d_in, const int* in_sizes, int n_in,
                              void* d_out, int out_size, void* d_ws, size_t ws_size,
                              hipStream_t stream) {
  const float* x      = (const float*)d_in[0];
  const float* W_attn = (const float*)d_in[1];
  const float* b_attn = (const float*)d_in[2];
  const float* W_proj = (const float*)d_in[3];
  const float* b_proj = (const float*)d_in[4];
  float* out = (float*)d_out;
  char* ws = (char*)d_ws;
  const size_t MB = (size_t)1 << 20;
  __bf16* xb  = (__bf16*)(ws + 0 * MB);
  __bf16* wab = (__bf16*)(ws + 8 * MB);
  __bf16* wpb = (__bf16*)(ws + 14 * MB);
  __bf16* qbf = (__bf16*)(ws + 16 * MB);
  __bf16* kbf = (__bf16*)(ws + 24 * MB);
  __bf16* vtb = (__bf16*)(ws + 32 * MB);
  __bf16* yb  = (__bf16*)(ws + 40 * MB);
  float*  lpt = (float*)(ws + 0 * MB);    // 512 KB over dead xb
  __bf16* opart = (__bf16*)d_out;         // 16.78 MB scratch; proj overwrites after

  cvt_bf16_all<<<4096, 256, 0, stream>>>(x, W_attn, W_proj, xb, wab, wpb);

  gemm_bt<1><<<dim3(24, 32), 256, 0, stream>>>(xb, wab, b_attn, nullptr,
                                               qbf, kbf, vtb, 4096, 3072, 1024);
  attn_fwd<<<dim3(32, 64), 64, 0, stream>>>(qbf, kbf, vtb, opart, lpt);
  attn_combine<<<2048, 256, 0, stream>>>(opart, lpt, yb);
  gemm_bt<0><<<dim3(8, 32), 256, 0, stream>>>(yb, wpb, b_proj, out,
                                              nullptr, nullptr, nullptr, 4096, 1024, 1024);
}

// Round 14
// 123.835 us; speedup vs baseline: 1.7004x; 1.1145x over previous
//
#include <hip/hip_runtime.h>

typedef __bf16 bf16x8 __attribute__((ext_vector_type(8)));
typedef __bf16 bf16x4 __attribute__((ext_vector_type(4)));
typedef float  f32x4  __attribute__((ext_vector_type(4)));
typedef float  f32x16 __attribute__((ext_vector_type(16)));

#define TSEQ 2048
#define CDIM 1024
#define NHEAD 16
#define DH 64
#define SCALE2 0.1803368801111137f  // 0.125 * log2(e)

__device__ __forceinline__ void gl_lds16(const void* g, void* l) {
  __builtin_amdgcn_global_load_lds(
      (const __attribute__((address_space(1))) unsigned int*)g,
      (__attribute__((address_space(3))) unsigned int*)l, 16, 0, 0);
}

__device__ __forceinline__ float fexp2(float x) { return __builtin_amdgcn_exp2f(x); }

__device__ __forceinline__ unsigned cvtpk(float a, float b) {
  unsigned r;
  asm("v_cvt_pk_bf16_f32 %0, %1, %2" : "=v"(r) : "v"(a), "v"(b));
  return r;
}
__device__ __forceinline__ void permswap(unsigned& x, unsigned& y) {
  asm("v_permlane32_swap_b32 %0, %1" : "+v"(x), "+v"(y));
}

__device__ __forceinline__ float tsum16(const f32x16& s) {
  float a0 = s[0] + s[1], a1 = s[2] + s[3], a2 = s[4] + s[5], a3 = s[6] + s[7];
  float a4 = s[8] + s[9], a5 = s[10] + s[11], a6 = s[12] + s[13], a7 = s[14] + s[15];
  float b0 = a0 + a1, b1 = a2 + a3, b2 = a4 + a5, b3 = a6 + a7;
  return (b0 + b1) + (b2 + b3);
}

// ---------------- fp32 -> bf16 conversion (merged, 1 launch) ----------------
__global__ __launch_bounds__(256) void cvt_bf16_all(
    const float* __restrict__ x, const float* __restrict__ wa,
    const float* __restrict__ wp, __bf16* __restrict__ xb,
    __bf16* __restrict__ wab, __bf16* __restrict__ wpb) {
  int i = blockIdx.x * 256 + threadIdx.x;  // 0..1048575 (x8 elems)
  const float* in;
  __bf16* out;
  int off;
  if (i < 524288)      { in = x;  out = xb;  off = i; }
  else if (i < 917504) { in = wa; out = wab; off = i - 524288; }
  else                 { in = wp; out = wpb; off = i - 917504; }
  const float4* p = (const float4*)(in + (size_t)off * 8);
  float4 a = p[0], b = p[1];
  bf16x8 r;
  r[0] = (__bf16)a.x; r[1] = (__bf16)a.y; r[2] = (__bf16)a.z; r[3] = (__bf16)a.w;
  r[4] = (__bf16)b.x; r[5] = (__bf16)b.y; r[6] = (__bf16)b.z; r[7] = (__bf16)b.w;
  *(bf16x8*)(out + (size_t)off * 8) = r;
}

// ---------------- bf16 GEMM 128x128 (m97 + T2 swizzle): qkv scatter epilogue ------
__global__ __launch_bounds__(256) void gemm_qkv(
    const __bf16* __restrict__ A, const __bf16* __restrict__ Bw,
    const float* __restrict__ bias,
    __bf16* __restrict__ q_buf, __bf16* __restrict__ k_buf,
    __bf16* __restrict__ vT_buf, int K) {
  __shared__ alignas(16) __bf16 lda[128 * 64];
  __shared__ alignas(16) __bf16 ldb[128 * 64];
  const int tid = threadIdx.x;
  const int lane = tid & 63, wid = tid >> 6;
  const int wm = wid >> 1, wn = wid & 1;
  const int row0 = blockIdx.y * 128, col0 = blockIdx.x * 128;
  f32x4 acc[4][4] = {};

  const int srow = lane >> 3;
  const int scb = ((lane & 7) ^ (lane >> 3)) * 16;

  for (int k0 = 0; k0 < K; k0 += 64) {
#pragma unroll
    for (int j = 0; j < 4; ++j) {
      int blk = j * 4 + wid;
      int r = blk * 8 + srow;
      char* la = (char*)lda + blk * 1024;
      char* lb = (char*)ldb + blk * 1024;
      gl_lds16((const char*)(A + (size_t)(row0 + r) * K + k0) + scb, la);
      gl_lds16((const char*)(Bw + (size_t)(col0 + r) * K + k0) + scb, lb);
    }
    __syncthreads();
#pragma unroll
    for (int kk = 0; kk < 2; ++kk) {
      const int sl = (((kk << 2) | (lane >> 4)) ^ (lane & 7)) * 16;
      bf16x8 af[4], bfr[4];
#pragma unroll
      for (int m = 0; m < 4; ++m)
        af[m] = *(const bf16x8*)((const char*)lda +
                                 (wm * 64 + m * 16 + (lane & 15)) * 128 + sl);
#pragma unroll
      for (int n = 0; n < 4; ++n)
        bfr[n] = *(const bf16x8*)((const char*)ldb +
                                  (wn * 64 + n * 16 + (lane & 15)) * 128 + sl);
#pragma unroll
      for (int m = 0; m < 4; ++m)
#pragma unroll
        for (int n = 0; n < 4; ++n)
          acc[m][n] = __builtin_amdgcn_mfma_f32_16x16x32_bf16(af[m], bfr[n], acc[m][n], 0, 0, 0);
    }
    __syncthreads();
  }
#pragma unroll
  for (int m = 0; m < 4; ++m) {
#pragma unroll
    for (int n = 0; n < 4; ++n) {
#pragma unroll
      for (int i = 0; i < 4; ++i) {
        int r = row0 + wm * 64 + m * 16 + (lane >> 4) * 4 + i;
        int c = col0 + wn * 64 + n * 16 + (lane & 15);
        float v = acc[m][n][i] + bias[c];
        int bb = r >> 11, t = r & 2047;
        int sec = c >> 10, cc = c & 1023;
        int hh = cc >> 6, d = cc & 63;
        size_t bh = (size_t)bb * NHEAD + hh;
        if (sec == 0)      q_buf[(bh * TSEQ + (size_t)t) * DH + d] = (__bf16)(v * SCALE2);
        else if (sec == 1) k_buf[(bh * TSEQ + (size_t)t) * DH + d] = (__bf16)v;
        else               vT_buf[(bh * DH + (size_t)d) * TSEQ + t] = (__bf16)v;
      }
    }
  }
}

// ---------------- proj GEMM 64x128 tiles (512 blocks -> 2/CU, latency-hiding) -----
__global__ __launch_bounds__(256) void gemm_proj(
    const __bf16* __restrict__ A, const __bf16* __restrict__ Bw,
    const float* __restrict__ bias, float* __restrict__ outf) {
  const int K = CDIM, N = CDIM;
  __shared__ alignas(16) __bf16 lda[64 * 64];
  __shared__ alignas(16) __bf16 ldb[128 * 64];
  const int tid = threadIdx.x;
  const int lane = tid & 63, wid = tid >> 6;
  const int row0 = blockIdx.y * 64, col0 = blockIdx.x * 128;
  f32x4 acc[4][2] = {};

  const int srow = lane >> 3;
  const int scb = ((lane & 7) ^ (lane >> 3)) * 16;

  for (int k0 = 0; k0 < K; k0 += 64) {
#pragma unroll
    for (int j = 0; j < 2; ++j) {  // A: 8 chunks of 8 rows
      int blk = j * 4 + wid;
      gl_lds16((const char*)(A + (size_t)(row0 + blk * 8 + srow) * K + k0) + scb,
               (char*)lda + blk * 1024);
    }
#pragma unroll
    for (int j = 0; j < 4; ++j) {  // B: 16 chunks
      int blk = j * 4 + wid;
      gl_lds16((const char*)(Bw + (size_t)(col0 + blk * 8 + srow) * K + k0) + scb,
               (char*)ldb + blk * 1024);
    }
    __syncthreads();
#pragma unroll
    for (int kk = 0; kk < 2; ++kk) {
      const int sl = (((kk << 2) | (lane >> 4)) ^ (lane & 7)) * 16;
      bf16x8 af[4], bfr[2];
#pragma unroll
      for (int m = 0; m < 4; ++m)
        af[m] = *(const bf16x8*)((const char*)lda + (m * 16 + (lane & 15)) * 128 + sl);
#pragma unroll
      for (int n = 0; n < 2; ++n)
        bfr[n] = *(const bf16x8*)((const char*)ldb +
                                  (wid * 32 + n * 16 + (lane & 15)) * 128 + sl);
#pragma unroll
      for (int m = 0; m < 4; ++m)
#pragma unroll
        for (int n = 0; n < 2; ++n)
          acc[m][n] = __builtin_amdgcn_mfma_f32_16x16x32_bf16(af[m], bfr[n], acc[m][n], 0, 0, 0);
    }
    __syncthreads();
  }
#pragma unroll
  for (int m = 0; m < 4; ++m) {
#pragma unroll
    for (int n = 0; n < 2; ++n) {
#pragma unroll
      for (int i = 0; i < 4; ++i) {
        int r = row0 + m * 16 + (lane >> 4) * 4 + i;
        int c = col0 + wid * 32 + n * 16 + (lane & 15);
        outf[(size_t)r * N + c] = acc[m][n][i] + bias[c];
      }
    }
  }
}

// ---------------- attention: fixed-ref softmax (R12 inner), no split-K ----------
__device__ __forceinline__ void softmax_pv(
    f32x16& s, bool domask, int lq, int hi,
    float& l_r, f32x16& o0, f32x16& o1,
    const bf16x8* va0, const bf16x8* va1) {
#pragma unroll
  for (int r = 0; r < 16; ++r) s[r] = fexp2(s[r]);
  if (domask) {
#pragma unroll
    for (int r = 0; r < 16; ++r) {
      int kof = (r & 3) + 8 * (r >> 2) + 4 * hi;
      if (kof > lq) s[r] = 0.f;
    }
  }
  l_r += tsum16(s);  // per-hi-half partial; cross-half shfl deferred to epilogue
  bf16x8 pb[2];
#pragma unroll
  for (int kh = 0; kh < 2; ++kh) {
    const int bq = kh * 8;
    unsigned w0 = cvtpk(s[bq + 0], s[bq + 1]);
    unsigned w1 = cvtpk(s[bq + 2], s[bq + 3]);
    unsigned w2 = cvtpk(s[bq + 4], s[bq + 5]);
    unsigned w3 = cvtpk(s[bq + 6], s[bq + 7]);
    permswap(w0, w2);
    permswap(w1, w3);
    union { unsigned u[4]; bf16x8 v; } pbu;
    pbu.u[0] = w0; pbu.u[1] = w1; pbu.u[2] = w2; pbu.u[3] = w3;
    pb[kh] = pbu.v;
  }
  o0 = __builtin_amdgcn_mfma_f32_32x32x16_bf16(va0[0], pb[0], o0, 0, 0, 0);
  o0 = __builtin_amdgcn_mfma_f32_32x32x16_bf16(va0[1], pb[1], o0, 0, 0, 0);
  o1 = __builtin_amdgcn_mfma_f32_32x32x16_bf16(va1[0], pb[0], o1, 0, 0, 0);
  o1 = __builtin_amdgcn_mfma_f32_32x32x16_bf16(va1[1], pb[1], o1, 0, 0, 0);
}

// ---------------- flash attention: swapped 32x32, paired chunks, direct y write ----
// 1 wave = pair {cH=63-wv, cL=wv}; loops all tiles j=0..cH (K/V loads shared by H+L).
// 1024 uniform-work blocks, heavy (long-loop) pairs dispatched first. No partials.
__global__ __launch_bounds__(64) void attn_fwd(
    const __bf16* __restrict__ q_buf, const __bf16* __restrict__ k_buf,
    const __bf16* __restrict__ vT_buf, __bf16* __restrict__ y_buf) {
  const int lane = threadIdx.x;
  const int lq = lane & 31;
  const int hi = lane >> 5;
  const int bh = blockIdx.x;
  const int wv = blockIdx.y;          // wv=0 (64-iter block) dispatched first
  const int b = bh >> 4, h = bh & 15;
  const int cH = 63 - wv, cL = wv;
  const float slope2 = exp2f(-0.5f * (float)(h + 1)) * 1.44269504f;
  const __bf16* qp = q_buf + (size_t)bh * TSEQ * DH;
  const __bf16* kp = k_buf + (size_t)bh * TSEQ * DH;
  const __bf16* vp = vT_buf + (size_t)bh * DH * TSEQ;

  bf16x8 qfH[4], qfL[4];
#pragma unroll
  for (int m = 0; m < 4; ++m) {
    qfH[m] = *(const bf16x8*)&qp[(size_t)(cH * 32 + lq) * DH + m * 16 + hi * 8];
    qfL[m] = *(const bf16x8*)&qp[(size_t)(cL * 32 + lq) * DH + m * 16 + hi * 8];
  }
  float pk_[16];
#pragma unroll
  for (int r = 0; r < 16; ++r)
    pk_[r] = slope2 * (float)((r & 3) + 8 * (r >> 2) + 4 * hi);

  f32x16 oH0 = {}, oH1 = {}, oL0 = {}, oL1 = {};
  float lH = 0.f, lL = 0.f;

  bf16x8 kf[4];
#pragma unroll
  for (int m = 0; m < 4; ++m)
    kf[m] = *(const bf16x8*)&kp[(size_t)lq * DH + m * 16 + hi * 8];

  for (int j = 0; j <= cH; ++j) {
    const int kt = j * 32;
    bf16x8 va0[2], va1[2];
#pragma unroll
    for (int kh = 0; kh < 2; ++kh) {
      va0[kh] = *(const bf16x8*)&vp[(size_t)lq * TSEQ + kt + kh * 16 + hi * 8];
      va1[kh] = *(const bf16x8*)&vp[(size_t)(32 + lq) * TSEQ + kt + kh * 16 + hi * 8];
    }
    bf16x8 kn[4];
    const bool pre = (j < cH);
    if (pre) {
#pragma unroll
      for (int m = 0; m < 4; ++m)
        kn[m] = *(const bf16x8*)&kp[(size_t)(kt + 32 + lq) * DH + m * 16 + hi * 8];
    }
    // bias as MFMA C-init: s starts at pk_ + slope2*(kt - q0)
    const float bH = slope2 * (float)(kt - cH * 32);
    f32x16 sH;
#pragma unroll
    for (int r = 0; r < 16; ++r) sH[r] = pk_[r] + bH;
#pragma unroll
    for (int m = 0; m < 4; ++m)
      sH = __builtin_amdgcn_mfma_f32_32x32x16_bf16(kf[m], qfH[m], sH, 0, 0, 0);
    const bool lact = (j <= cL);
    f32x16 sL;
    if (lact) {
      const float bL = slope2 * (float)(kt - cL * 32);
#pragma unroll
      for (int r = 0; r < 16; ++r) sL[r] = pk_[r] + bL;
#pragma unroll
      for (int m = 0; m < 4; ++m)
        sL = __builtin_amdgcn_mfma_f32_32x32x16_bf16(kf[m], qfL[m], sL, 0, 0, 0);
    }
    softmax_pv(sH, j == cH, lq, hi, lH, oH0, oH1, va0, va1);
    if (lact)
      softmax_pv(sL, j == cL, lq, hi, lL, oL0, oL1, va0, va1);
    if (pre) {
#pragma unroll
      for (int m = 0; m < 4; ++m) kf[m] = kn[m];
    }
  }
  // deferred cross-half l reduction (once)
  lH += __shfl_xor(lH, 32, 64);
  lL += __shfl_xor(lL, 32, 64);

  // normalized direct write: lane owns q-row t = c*32+lq; d = 8g+4hi+e (+32 for o1)
#pragma unroll
  for (int g2 = 0; g2 < 2; ++g2) {
    const int c = g2 ? cL : cH;
    const f32x16& a0 = g2 ? oL0 : oH0;
    const f32x16& a1 = g2 ? oL1 : oH1;
    const float inv = 1.0f / (g2 ? lL : lH);
    __bf16* yb = y_buf + ((size_t)b * TSEQ + c * 32 + lq) * CDIM + h * DH;
#pragma unroll
    for (int g = 0; g < 4; ++g) {
      bf16x4 v0, v1;
#pragma unroll
      for (int e = 0; e < 4; ++e) {
        v0[e] = (__bf16)(a0[4 * g + e] * inv);
        v1[e] = (__bf16)(a1[4 * g + e] * inv);
      }
      *(bf16x4*)&yb[8 * g + 4 * hi] = v0;
      *(bf16x4*)&yb[32 + 8 * g + 4 * hi] = v1;
    }
  }
}

extern "C" void kernel_launch(void* const* d_in, const int* in_sizes, int n_in,
                              void* d_out, int out_size, void* d_ws, size_t ws_size,
                              hipStream_t stream) {
  const float* x      = (const float*)d_in[0];
  const float* W_attn = (const float*)d_in[1];
  const float* b_attn = (const float*)d_in[2];
  const float* W_proj = (const float*)d_in[3];
  const float* b_proj = (const float*)d_in[4];
  float* out = (float*)d_out;
  char* ws = (char*)d_ws;
  const size_t MB = (size_t)1 << 20;
  __bf16* xb  = (__bf16*)(ws + 0 * MB);
  __bf16* wab = (__bf16*)(ws + 8 * MB);
  __bf16* wpb = (__bf16*)(ws + 14 * MB);
  __bf16* qbf = (__bf16*)(ws + 16 * MB);
  __bf16* kbf = (__bf16*)(ws + 24 * MB);
  __bf16* vtb = (__bf16*)(ws + 32 * MB);
  __bf16* yb  = (__bf16*)(ws + 40 * MB);

  cvt_bf16_all<<<4096, 256, 0, stream>>>(x, W_attn, W_proj, xb, wab, wpb);

  gemm_qkv<<<dim3(24, 32), 256, 0, stream>>>(xb, wab, b_attn, qbf, kbf, vtb, 1024);
  attn_fwd<<<dim3(32, 32), 64, 0, stream>>>(qbf, kbf, vtb, yb);
  gemm_proj<<<dim3(8, 64), 256, 0, stream>>>(yb, wpb, b_proj, out);
}